// Round 2
// baseline (2929.244 us; speedup 1.0000x reference)
//
#include <hip/hip_runtime.h>
#include <hip/hip_bf16.h>

#define NN 50000
#define NE 800000
#define DD 128
#define BN_EPS 1e-5f

__device__ __forceinline__ void atomAdd(float* p, float v) { unsafeAtomicAdd(p, v); }

// deg[dst] += 1
__global__ void deg_kernel(const int* __restrict__ dst, float* __restrict__ deg) {
    int e = blockIdx.x * 256 + threadIdx.x;
    if (e < NE) atomAdd(&deg[dst[e]], 1.0f);
}

// deg -> rsqrt(max(deg,1)) in place
__global__ void norm_kernel(float* __restrict__ deg) {
    int i = blockIdx.x * 256 + threadIdx.x;
    if (i < NN) deg[i] = rsqrtf(fmaxf(deg[i], 1.0f));
}

// agg[dst] += x[src] * norm[src]; 32 lanes per edge, 4 elems per lane
__global__ void scatter_f32(const float* __restrict__ x,
                            const float* __restrict__ norm,
                            const int* __restrict__ src,
                            const int* __restrict__ dst,
                            float* __restrict__ agg) {
    int tid = blockIdx.x * 256 + threadIdx.x;
    int e = tid >> 5;
    if (e >= NE) return;
    int c = (tid & 31) << 2;
    int s = src[e], dv = dst[e];
    float ns = norm[s];
    float4 v = *reinterpret_cast<const float4*>(x + (size_t)s * DD + c);
    float* ap = agg + (size_t)dv * DD + c;
    atomAdd(ap + 0, v.x * ns);
    atomAdd(ap + 1, v.y * ns);
    atomAdd(ap + 2, v.z * ns);
    atomAdd(ap + 3, v.w * ns);
}

// x[i][:] *= norm[i]   (vec4 over N*D)
__global__ void rowscale(float* __restrict__ x, const float* __restrict__ norm) {
    int t = blockIdx.x * 256 + threadIdx.x;
    if (t >= NN * DD / 4) return;
    float nv = norm[t >> 5];
    float4* p = reinterpret_cast<float4*>(x) + t;
    float4 v = *p;
    v.x *= nv; v.y *= nv; v.z *= nv; v.w *= nv;
    *p = v;
}

// t = (feat@(W1-W3) + ax@(-W2) + ax2@(2W3) + bias) * snorm; BN partial sums.
// 16 rows per block, 256 threads: d = tid&127, rowgroup = tid>>7 (8 rows each).
__global__ __launch_bounds__(256) void linear_bn_partial(
    const float* __restrict__ feat,
    const float* ax,                 // aliased with tout (block-private rows, staged via LDS)
    const float* __restrict__ ax2,
    const float* __restrict__ snorm,
    const float* __restrict__ W1,
    const float* __restrict__ W2,
    const float* __restrict__ W3,
    const float* __restrict__ bias,
    float* tout,
    float* __restrict__ gsums, float* __restrict__ gsq)
{
    __shared__ float sf[16][132], sax[16][132], sax2[16][132];
    __shared__ float ps[2][128], pq[2][128];
    int tid = threadIdx.x;
    int row0 = blockIdx.x * 16;

    // stage 16 rows of feat/ax/ax2 into LDS (8 elems per thread)
    {
        int lr = tid >> 4;
        int ld = (tid & 15) << 3;
        size_t base = (size_t)(row0 + lr) * DD + ld;
        float4 f0 = *reinterpret_cast<const float4*>(feat + base);
        float4 f1 = *reinterpret_cast<const float4*>(feat + base + 4);
        sf[lr][ld + 0] = f0.x; sf[lr][ld + 1] = f0.y; sf[lr][ld + 2] = f0.z; sf[lr][ld + 3] = f0.w;
        sf[lr][ld + 4] = f1.x; sf[lr][ld + 5] = f1.y; sf[lr][ld + 6] = f1.z; sf[lr][ld + 7] = f1.w;
        float4 x0 = *reinterpret_cast<const float4*>(ax + base);
        float4 x1 = *reinterpret_cast<const float4*>(ax + base + 4);
        sax[lr][ld + 0] = x0.x; sax[lr][ld + 1] = x0.y; sax[lr][ld + 2] = x0.z; sax[lr][ld + 3] = x0.w;
        sax[lr][ld + 4] = x1.x; sax[lr][ld + 5] = x1.y; sax[lr][ld + 6] = x1.z; sax[lr][ld + 7] = x1.w;
        float4 y0 = *reinterpret_cast<const float4*>(ax2 + base);
        float4 y1 = *reinterpret_cast<const float4*>(ax2 + base + 4);
        sax2[lr][ld + 0] = y0.x; sax2[lr][ld + 1] = y0.y; sax2[lr][ld + 2] = y0.z; sax2[lr][ld + 3] = y0.w;
        sax2[lr][ld + 4] = y1.x; sax2[lr][ld + 5] = y1.y; sax2[lr][ld + 6] = y1.z; sax2[lr][ld + 7] = y1.w;
    }
    __syncthreads();

    int d = tid & 127;
    int rg = tid >> 7;
    float acc[8] = {0.f, 0.f, 0.f, 0.f, 0.f, 0.f, 0.f, 0.f};
    #pragma unroll 2
    for (int k = 0; k < DD; ++k) {
        float w1 = W1[k * DD + d];
        float w2 = W2[k * DD + d];
        float w3 = W3[k * DD + d];
        float cf = w1 - w3;
        float ca = -w2;
        float c2 = 2.0f * w3;
        #pragma unroll
        for (int r = 0; r < 8; ++r) {
            int rr = rg * 8 + r;
            acc[r] = fmaf(sf[rr][k], cf, acc[r]);
            acc[r] = fmaf(sax[rr][k], ca, acc[r]);
            acc[r] = fmaf(sax2[rr][k], c2, acc[r]);
        }
    }

    float bs = bias[d];
    float s1 = 0.f, s2 = 0.f;
    #pragma unroll
    for (int r = 0; r < 8; ++r) {
        int row = row0 + rg * 8 + r;
        float t = (acc[r] + bs) * snorm[row];
        tout[(size_t)row * DD + d] = t;
        s1 += t; s2 += t * t;
    }
    ps[rg][d] = s1; pq[rg][d] = s2;
    __syncthreads();
    if (rg == 0) {
        int slot = (blockIdx.x & 31) * DD + d;
        atomAdd(&gsums[slot], ps[0][d] + ps[1][d]);
        atomAdd(&gsq[slot],   pq[0][d] + pq[1][d]);
    }
}

__global__ void bn_finalize(const float* __restrict__ gsums, const float* __restrict__ gsq,
                            const float* __restrict__ gamma,
                            const float* __restrict__ beta,
                            float* __restrict__ scale, float* __restrict__ shift) {
    int d = threadIdx.x;  // 128
    float s1 = 0.f, s2 = 0.f;
    for (int c = 0; c < 32; ++c) { s1 += gsums[c * DD + d]; s2 += gsq[c * DD + d]; }
    float mean = s1 / (float)NN;
    float var  = s2 / (float)NN - mean * mean;
    float sc = gamma[d] * rsqrtf(var + BN_EPS);
    scale[d] = sc;
    shift[d] = beta[d] - mean * sc;
}

// out = feat + relu(t*scale + shift)
__global__ void epilogue(const float* __restrict__ t, const float* __restrict__ feat,
                         const float* __restrict__ scale, const float* __restrict__ shift,
                         float* __restrict__ out) {
    int i = blockIdx.x * 256 + threadIdx.x;  // over N*D/4
    if (i >= NN * DD / 4) return;
    int d0 = (i << 2) & 127;
    float4 tv = reinterpret_cast<const float4*>(t)[i];
    float4 fv = reinterpret_cast<const float4*>(feat)[i];
    float4 o;
    o.x = fv.x + fmaxf(tv.x * scale[d0 + 0] + shift[d0 + 0], 0.f);
    o.y = fv.y + fmaxf(tv.y * scale[d0 + 1] + shift[d0 + 1], 0.f);
    o.z = fv.z + fmaxf(tv.z * scale[d0 + 2] + shift[d0 + 2], 0.f);
    o.w = fv.w + fmaxf(tv.w * scale[d0 + 3] + shift[d0 + 3], 0.f);
    reinterpret_cast<float4*>(out)[i] = o;
}

extern "C" void kernel_launch(void* const* d_in, const int* in_sizes, int n_in,
                              void* d_out, int out_size, void* d_ws, size_t ws_size,
                              hipStream_t stream) {
    const float* feat  = (const float*)d_in[0];
    const float* snorm = (const float*)d_in[1];
    const float* W1    = (const float*)d_in[2];
    const float* W2    = (const float*)d_in[3];
    const float* W3    = (const float*)d_in[4];
    const float* bias  = (const float*)d_in[5];
    const float* gamma = (const float*)d_in[6];
    const float* beta  = (const float*)d_in[7];
    const int* esrc = (const int*)d_in[8];
    const int* edst = (const int*)d_in[9];
    float* out = (float*)d_out;

    char* ws = (char*)d_ws;
    float* A     = (float*)(ws);               // 25,600,000 B : agg1 / ax / t
    float* B     = (float*)(ws + 25600000);    // 25,600,000 B : agg2 / ax2
    float* norm  = (float*)(ws + 51200000);    //    200,000 B : deg -> norm
    float* gsums = (float*)(ws + 51400000);    //     16,384 B
    float* gsq   = (float*)(ws + 51416384);    //     16,384 B
    float* scale = (float*)(ws + 51432768);    //        512 B
    float* shift = (float*)(ws + 51433280);    //        512 B

    hipMemsetAsync(d_ws, 0, 51432768, stream); // zero A, B, norm, gsums, gsq

    deg_kernel <<<3125, 256, 0, stream>>>(edst, norm);
    norm_kernel<<<196,  256, 0, stream>>>(norm);

    scatter_f32<<<100000, 256, 0, stream>>>(feat, norm, esrc, edst, A);
    rowscale   <<<6250,   256, 0, stream>>>(A, norm);           // A = ax
    scatter_f32<<<100000, 256, 0, stream>>>(A, norm, esrc, edst, B);
    rowscale   <<<6250,   256, 0, stream>>>(B, norm);           // B = ax2

    linear_bn_partial<<<3125, 256, 0, stream>>>(feat, A, B, snorm,
                                                W1, W2, W3, bias, A, gsums, gsq);
    bn_finalize<<<1, 128, 0, stream>>>(gsums, gsq, gamma, beta, scale, shift);
    epilogue   <<<6250, 256, 0, stream>>>(A, feat, scale, shift, out);
}

// Round 3
// 500.942 us; speedup vs baseline: 5.8475x; 5.8475x over previous
//
#include <hip/hip_runtime.h>
#include <hip/hip_bf16.h>

#define NN 50000
#define NE 800000
#define DD 128
#define BN_EPS 1e-5f

__device__ __forceinline__ void atomAdd(float* p, float v) { unsafeAtomicAdd(p, v); }

// deg[dst] += 1  (int)
__global__ void deg_kernel(const int* __restrict__ dst, int* __restrict__ deg) {
    int e = blockIdx.x * 256 + threadIdx.x;
    if (e < NE) atomicAdd(&deg[dst[e]], 1);
}

// norm = rsqrt(max(deg,1))
__global__ void norm_kernel(const int* __restrict__ deg, float* __restrict__ norm) {
    int i = blockIdx.x * 256 + threadIdx.x;
    if (i < NN) norm[i] = rsqrtf((float)max(deg[i], 1));
}

// single-block exclusive scan of deg -> off[0..NN], cursor copy
__global__ __launch_bounds__(1024) void scan_kernel(const int* __restrict__ deg,
                                                    int* __restrict__ off,
                                                    int* __restrict__ cursor) {
    __shared__ int part[1024];
    int t = threadIdx.x;
    const int CH = 49;                      // 1024*49 = 50176 >= NN
    int beg = t * CH, end = min(beg + CH, NN);
    int sum = 0;
    for (int i = beg; i < end; ++i) sum += deg[i];
    part[t] = sum;
    __syncthreads();
    for (int s = 1; s < 1024; s <<= 1) {
        int v = (t >= s) ? part[t - s] : 0;
        __syncthreads();
        part[t] += v;
        __syncthreads();
    }
    int run = t ? part[t - 1] : 0;
    for (int i = beg; i < end; ++i) {
        off[i] = run; cursor[i] = run; run += deg[i];
    }
    if (t == 1023) off[NN] = part[1023];    // total = NE
}

// bucket edges by dst: csr_src[pos] = src, csr_ns[pos] = norm[src]
__global__ void csr_fill(const int* __restrict__ src, const int* __restrict__ dst,
                         const float* __restrict__ norm,
                         int* __restrict__ cursor,
                         int* __restrict__ csr_src, float* __restrict__ csr_ns) {
    int e = blockIdx.x * 256 + threadIdx.x;
    if (e >= NE) return;
    int s = src[e];
    int pos = atomicAdd(&cursor[dst[e]], 1);
    csr_src[pos] = s;
    csr_ns[pos] = norm[s];
}

// out[d,:] = norm[d] * sum_{e in in(d)} norm[src_e] * x[src_e,:]
// one wave (64 lanes) per node; lane handles float2 (cols 2l, 2l+1)
__global__ __launch_bounds__(256) void gather_mp(const float* __restrict__ x,
                                                 const float* __restrict__ norm,
                                                 const int* __restrict__ off,
                                                 const int* __restrict__ csr_src,
                                                 const float* __restrict__ csr_ns,
                                                 float* __restrict__ out) {
    int wid = (blockIdx.x << 2) + (threadIdx.x >> 6);   // node id, grid exact
    int lane = threadIdx.x & 63;
    int jb = off[wid], je = off[wid + 1];
    const float2* xp = reinterpret_cast<const float2*>(x);
    float ax = 0.f, ay = 0.f;
    int j = jb;
    int s_n = 0; float ns_n = 0.f;
    if (j < je) { s_n = csr_src[j]; ns_n = csr_ns[j]; }
    while (j < je) {
        int s = s_n; float ns = ns_n;
        ++j;
        if (j < je) { s_n = csr_src[j]; ns_n = csr_ns[j]; }
        float2 v = xp[s * 64 + lane];
        ax = fmaf(ns, v.x, ax);
        ay = fmaf(ns, v.y, ay);
    }
    float nd = norm[wid];
    reinterpret_cast<float2*>(out)[wid * 64 + lane] = make_float2(nd * ax, nd * ay);
}

// t = (feat@(W1-W3) + ax@(-W2) + ax2@(2W3) + bias) * snorm; BN partial sums.
// 16 rows per block, 256 threads: d = tid&127, rowgroup = tid>>7 (8 rows each).
__global__ __launch_bounds__(256) void linear_bn_partial(
    const float* __restrict__ feat,
    const float* ax,                 // aliased with tout (block-private rows via LDS)
    const float* __restrict__ ax2,
    const float* __restrict__ snorm,
    const float* __restrict__ W1,
    const float* __restrict__ W2,
    const float* __restrict__ W3,
    const float* __restrict__ bias,
    float* tout,
    float* __restrict__ gsums, float* __restrict__ gsq)
{
    __shared__ float sf[16][132], sax[16][132], sax2[16][132];
    __shared__ float ps[2][128], pq[2][128];
    int tid = threadIdx.x;
    int row0 = blockIdx.x * 16;

    {
        int lr = tid >> 4;
        int ld = (tid & 15) << 3;
        size_t base = (size_t)(row0 + lr) * DD + ld;
        float4 f0 = *reinterpret_cast<const float4*>(feat + base);
        float4 f1 = *reinterpret_cast<const float4*>(feat + base + 4);
        sf[lr][ld + 0] = f0.x; sf[lr][ld + 1] = f0.y; sf[lr][ld + 2] = f0.z; sf[lr][ld + 3] = f0.w;
        sf[lr][ld + 4] = f1.x; sf[lr][ld + 5] = f1.y; sf[lr][ld + 6] = f1.z; sf[lr][ld + 7] = f1.w;
        float4 x0 = *reinterpret_cast<const float4*>(ax + base);
        float4 x1 = *reinterpret_cast<const float4*>(ax + base + 4);
        sax[lr][ld + 0] = x0.x; sax[lr][ld + 1] = x0.y; sax[lr][ld + 2] = x0.z; sax[lr][ld + 3] = x0.w;
        sax[lr][ld + 4] = x1.x; sax[lr][ld + 5] = x1.y; sax[lr][ld + 6] = x1.z; sax[lr][ld + 7] = x1.w;
        float4 y0 = *reinterpret_cast<const float4*>(ax2 + base);
        float4 y1 = *reinterpret_cast<const float4*>(ax2 + base + 4);
        sax2[lr][ld + 0] = y0.x; sax2[lr][ld + 1] = y0.y; sax2[lr][ld + 2] = y0.z; sax2[lr][ld + 3] = y0.w;
        sax2[lr][ld + 4] = y1.x; sax2[lr][ld + 5] = y1.y; sax2[lr][ld + 6] = y1.z; sax2[lr][ld + 7] = y1.w;
    }
    __syncthreads();

    int d = tid & 127;
    int rg = tid >> 7;
    float acc[8] = {0.f, 0.f, 0.f, 0.f, 0.f, 0.f, 0.f, 0.f};
    #pragma unroll 2
    for (int k = 0; k < DD; ++k) {
        float w1 = W1[k * DD + d];
        float w2 = W2[k * DD + d];
        float w3 = W3[k * DD + d];
        float cf = w1 - w3;
        float ca = -w2;
        float c2 = 2.0f * w3;
        #pragma unroll
        for (int r = 0; r < 8; ++r) {
            int rr = rg * 8 + r;
            acc[r] = fmaf(sf[rr][k], cf, acc[r]);
            acc[r] = fmaf(sax[rr][k], ca, acc[r]);
            acc[r] = fmaf(sax2[rr][k], c2, acc[r]);
        }
    }

    float bs = bias[d];
    float s1 = 0.f, s2 = 0.f;
    #pragma unroll
    for (int r = 0; r < 8; ++r) {
        int row = row0 + rg * 8 + r;
        float t = (acc[r] + bs) * snorm[row];
        tout[(size_t)row * DD + d] = t;
        s1 += t; s2 += t * t;
    }
    ps[rg][d] = s1; pq[rg][d] = s2;
    __syncthreads();
    if (rg == 0) {
        int slot = (blockIdx.x & 31) * DD + d;
        atomAdd(&gsums[slot], ps[0][d] + ps[1][d]);
        atomAdd(&gsq[slot],   pq[0][d] + pq[1][d]);
    }
}

__global__ void bn_finalize(const float* __restrict__ gsums, const float* __restrict__ gsq,
                            const float* __restrict__ gamma,
                            const float* __restrict__ beta,
                            float* __restrict__ scale, float* __restrict__ shift) {
    int d = threadIdx.x;  // 128
    float s1 = 0.f, s2 = 0.f;
    for (int c = 0; c < 32; ++c) { s1 += gsums[c * DD + d]; s2 += gsq[c * DD + d]; }
    float mean = s1 / (float)NN;
    float var  = s2 / (float)NN - mean * mean;
    float sc = gamma[d] * rsqrtf(var + BN_EPS);
    scale[d] = sc;
    shift[d] = beta[d] - mean * sc;
}

// out = feat + relu(t*scale + shift)
__global__ void epilogue(const float* __restrict__ t, const float* __restrict__ feat,
                         const float* __restrict__ scale, const float* __restrict__ shift,
                         float* __restrict__ out) {
    int i = blockIdx.x * 256 + threadIdx.x;  // over N*D/4
    if (i >= NN * DD / 4) return;
    int d0 = (i << 2) & 127;
    float4 tv = reinterpret_cast<const float4*>(t)[i];
    float4 fv = reinterpret_cast<const float4*>(feat)[i];
    float4 o;
    o.x = fv.x + fmaxf(tv.x * scale[d0 + 0] + shift[d0 + 0], 0.f);
    o.y = fv.y + fmaxf(tv.y * scale[d0 + 1] + shift[d0 + 1], 0.f);
    o.z = fv.z + fmaxf(tv.z * scale[d0 + 2] + shift[d0 + 2], 0.f);
    o.w = fv.w + fmaxf(tv.w * scale[d0 + 3] + shift[d0 + 3], 0.f);
    reinterpret_cast<float4*>(out)[i] = o;
}

extern "C" void kernel_launch(void* const* d_in, const int* in_sizes, int n_in,
                              void* d_out, int out_size, void* d_ws, size_t ws_size,
                              hipStream_t stream) {
    const float* feat  = (const float*)d_in[0];
    const float* snorm = (const float*)d_in[1];
    const float* W1    = (const float*)d_in[2];
    const float* W2    = (const float*)d_in[3];
    const float* W3    = (const float*)d_in[4];
    const float* bias  = (const float*)d_in[5];
    const float* gamma = (const float*)d_in[6];
    const float* beta  = (const float*)d_in[7];
    const int* esrc = (const int*)d_in[8];
    const int* edst = (const int*)d_in[9];
    float* out = (float*)d_out;

    char* ws = (char*)d_ws;
    float* B1     = (float*)(ws);                 // 25,600,000 : ax / t (aliased)
    float* B2     = (float*)(ws + 25600000);      // 25,600,000 : ax2
    float* norm   = (float*)(ws + 51200000);      //    200,000
    int*   deg    = (int*)  (ws + 51400000);      //    200,000  <- memset
    float* gsums  = (float*)(ws + 51600000);      //     16,384  <- memset
    float* gsq    = (float*)(ws + 51616384);      //     16,384  <- memset
    float* scale  = (float*)(ws + 51632768);      //        512
    float* shift  = (float*)(ws + 51633280);      //        512
    int*   off    = (int*)  (ws + 51633792);      //    200,064 (NN+1 ints, padded)
    int*   cursor = (int*)  (ws + 51833856);      //    200,000
    int*   csrs   = (int*)  (ws + 52033856);      //  3,200,000
    float* csrn   = (float*)(ws + 55233856);      //  3,200,000  (total 58,433,856)

    hipMemsetAsync(ws + 51400000, 0, 232768, stream);   // deg, gsums, gsq

    deg_kernel <<<3125, 256, 0, stream>>>(edst, deg);
    norm_kernel<<<196,  256, 0, stream>>>(deg, norm);
    scan_kernel<<<1, 1024, 0, stream>>>(deg, off, cursor);
    csr_fill   <<<3125, 256, 0, stream>>>(esrc, edst, norm, cursor, csrs, csrn);

    gather_mp<<<12500, 256, 0, stream>>>(feat, norm, off, csrs, csrn, B1);  // B1 = ax
    gather_mp<<<12500, 256, 0, stream>>>(B1,   norm, off, csrs, csrn, B2);  // B2 = ax2

    linear_bn_partial<<<3125, 256, 0, stream>>>(feat, B1, B2, snorm,
                                                W1, W2, W3, bias, B1, gsums, gsq);
    bn_finalize<<<1, 128, 0, stream>>>(gsums, gsq, gamma, beta, scale, shift);
    epilogue   <<<6250, 256, 0, stream>>>(B1, feat, scale, shift, out);
}

// Round 4
// 367.678 us; speedup vs baseline: 7.9669x; 1.3624x over previous
//
#include <hip/hip_runtime.h>
#include <hip/hip_bf16.h>

#define NN 50000
#define NE 800000
#define DD 128
#define BN_EPS 1e-5f

typedef unsigned short ushort_t;
typedef unsigned int uint_t;
typedef __attribute__((ext_vector_type(8))) short short8v;   // 8 x bf16 (4 VGPR)
typedef __attribute__((ext_vector_type(4))) float f32x4;

__device__ __forceinline__ float b2f(ushort_t u) {
    union { uint_t i; float f; } v; v.i = ((uint_t)u) << 16; return v.f;
}
__device__ __forceinline__ ushort_t f2b(float f) {
    uint_t u = __float_as_uint(f);
    u += 0x7FFFu + ((u >> 16) & 1u);   // RNE
    return (ushort_t)(u >> 16);
}
__device__ __forceinline__ void atomAdd(float* p, float v) { unsafeAtomicAdd(p, v); }

// ---------- graph prep ----------
__global__ void deg_kernel(const int* __restrict__ dst, int* __restrict__ deg) {
    int e = blockIdx.x * 256 + threadIdx.x;
    if (e < NE) atomicAdd(&deg[dst[e]], 1);
}

__global__ void norm_kernel(const int* __restrict__ deg, float* __restrict__ norm) {
    int i = blockIdx.x * 256 + threadIdx.x;
    if (i < NN) norm[i] = rsqrtf((float)max(deg[i], 1));
}

// exclusive scan of deg -> off[0..NN]; cursor (ALIASED with deg) gets copy.
__global__ __launch_bounds__(1024) void scan_kernel(const int* __restrict__ deg,
                                                    int* __restrict__ off,
                                                    int* __restrict__ cursor) {
    __shared__ int part[1024];
    int t = threadIdx.x;
    const int CH = 49;
    int beg = t * CH, end = min(beg + CH, NN);
    int sum = 0;
    for (int i = beg; i < end; ++i) sum += deg[i];
    part[t] = sum;
    __syncthreads();
    for (int s = 1; s < 1024; s <<= 1) {
        int v = (t >= s) ? part[t - s] : 0;
        __syncthreads();
        part[t] += v;
        __syncthreads();
    }
    int run = t ? part[t - 1] : 0;
    for (int i = beg; i < end; ++i) {
        int dv = deg[i];            // read BEFORE cursor write (deg==cursor alias)
        off[i] = run; cursor[i] = run; run += dv;
    }
    if (t == 1023) off[NN] = part[1023];
}

__global__ void csr_fill(const int* __restrict__ src, const int* __restrict__ dst,
                         const float* __restrict__ norm,
                         int* __restrict__ cursor,
                         int* __restrict__ csr_src, float* __restrict__ csr_ns) {
    int e = blockIdx.x * 256 + threadIdx.x;
    if (e >= NE) return;
    int s = src[e];
    int pos = atomicAdd(&cursor[dst[e]], 1);
    csr_src[pos] = s;
    csr_ns[pos] = norm[s];
}

// ---------- conversions ----------
__global__ void f2bf_kernel(const float* __restrict__ in, ushort_t* __restrict__ out) {
    int i = blockIdx.x * 256 + threadIdx.x;   // per 4 elems
    if (i >= NN * DD / 4) return;
    float4 v = reinterpret_cast<const float4*>(in)[i];
    ushort4 o = { f2b(v.x), f2b(v.y), f2b(v.z), f2b(v.w) };
    reinterpret_cast<ushort4*>(out)[i] = o;
}

// WcT[d][k] (128 x 384 bf16): k<128: W1-W3; k<256: -W2; else 2*W3
__global__ void wct_kernel(const float* __restrict__ W1, const float* __restrict__ W2,
                           const float* __restrict__ W3, ushort_t* __restrict__ wcT) {
    int i = blockIdx.x * 256 + threadIdx.x;
    if (i >= DD * 384) return;
    int d = i / 384, k = i % 384;
    float v;
    if (k < 128)      v = W1[k * DD + d] - W3[k * DD + d];
    else if (k < 256) v = -W2[(k - 128) * DD + d];
    else              v = 2.0f * W3[(k - 256) * DD + d];
    wcT[i] = f2b(v);
}

// ---------- message passing (bf16 in, bf16 out) ----------
// out[d,:] = bf16( norm[d] * sum_e norm[src_e] * x[src_e,:] ); wave per node
__global__ __launch_bounds__(256) void gather_bf(const ushort_t* __restrict__ x,
                                                 const float* __restrict__ norm,
                                                 const int* __restrict__ off,
                                                 const int* __restrict__ csr_src,
                                                 const float* __restrict__ csr_ns,
                                                 ushort_t* __restrict__ out) {
    int wid = (blockIdx.x << 2) + (threadIdx.x >> 6);
    int lane = threadIdx.x & 63;
    int jb = off[wid], je = off[wid + 1];
    const uint_t* xp = reinterpret_cast<const uint_t*>(x);
    float ax = 0.f, ay = 0.f;
    int j = jb;
    int s_n = 0; float ns_n = 0.f;
    if (j < je) { s_n = csr_src[j]; ns_n = csr_ns[j]; }
    while (j < je) {
        int s = s_n; float ns = ns_n;
        ++j;
        if (j < je) { s_n = csr_src[j]; ns_n = csr_ns[j]; }
        uint_t v = xp[s * 64 + lane];
        ax = fmaf(ns, b2f((ushort_t)v), ax);
        ay = fmaf(ns, b2f((ushort_t)(v >> 16)), ay);
    }
    float nd = norm[wid];
    uint_t o = (uint_t)f2b(nd * ax) | ((uint_t)f2b(nd * ay) << 16);
    reinterpret_cast<uint_t*>(out)[wid * 64 + lane] = o;
}

// ---------- MFMA GEMM + BN partials ----------
// t[row][col] = (sum_k X[row][k]*Wc[k][col] + bias[col]) * snorm[row]
// X = [feat_bf | ax_bf | ax2_bf]  (K=384), block = 64 rows, 4 waves,
// wave w owns rows w*16..w*16+15, all 128 cols (8 col-frags).
__global__ __launch_bounds__(256) void gemm_bn(
    const ushort_t* __restrict__ feat_bf, const ushort_t* __restrict__ ax_bf,
    const ushort_t* __restrict__ ax2_bf, const ushort_t* __restrict__ wcT,
    const float* __restrict__ bias, const float* __restrict__ snorm,
    ushort_t* __restrict__ t_out, float* __restrict__ gsums, float* __restrict__ gsq)
{
    __shared__ ushort_t As[64 * 128];    // 16 KB, XOR-swizzled
    __shared__ ushort_t Bs[128 * 128];   // 32 KB, XOR-swizzled
    int tid = threadIdx.x;
    int w = tid >> 6, lane = tid & 63;
    int row0 = blockIdx.x * 64;

    f32x4 acc[8] = {};

    #pragma unroll
    for (int kt = 0; kt < 3; ++kt) {
        const ushort_t* S = (kt == 0) ? feat_bf : (kt == 1) ? ax_bf : ax2_bf;
        __syncthreads();   // previous iteration's reads complete
        // stage A-tile: 64 rows x 128 k
        {
            int r = tid >> 2, q = tid & 3;
            int grow = min(row0 + r, NN - 1);
            const char* gsrc = (const char*)(S + grow * DD);
            char* dbase = (char*)As + r * 256;
            int sw = (r & 7) << 4;
            #pragma unroll
            for (int c = 0; c < 4; ++c) {
                int cb = (q * 4 + c) * 16;
                *(short8v*)(dbase + (cb ^ sw)) = *(const short8v*)(gsrc + cb);
            }
        }
        // stage B^T slice: 128 cols x 128 k  (WcT row-major [128][384])
        {
            int cidx = tid >> 1, h = tid & 1;
            const char* gsrc = (const char*)(wcT + cidx * 384 + kt * 128);
            char* dbase = (char*)Bs + cidx * 256;
            int sw = (cidx & 7) << 4;
            #pragma unroll
            for (int c = 0; c < 8; ++c) {
                int cb = (h * 8 + c) * 16;
                *(short8v*)(dbase + (cb ^ sw)) = *(const short8v*)(gsrc + cb);
            }
        }
        __syncthreads();
        // 4 K-steps of 32
        int arow = w * 16 + (lane & 15);
        int asw = (arow & 7) << 4;
        #pragma unroll
        for (int ks = 0; ks < 4; ++ks) {
            int kb = ks * 64 + ((lane >> 4) << 4);   // byte offset of this lane's k-group
            short8v a = *(const short8v*)((const char*)As + arow * 256 + (kb ^ asw));
            #pragma unroll
            for (int cf = 0; cf < 8; ++cf) {
                int col = cf * 16 + (lane & 15);
                short8v b = *(const short8v*)((const char*)Bs + col * 256 + (kb ^ ((col & 7) << 4)));
                acc[cf] = __builtin_amdgcn_mfma_f32_16x16x32_bf16(a, b, acc[cf], 0, 0, 0);
            }
        }
    }

    // epilogue: t = (acc+bias)*snorm, store bf16, BN partial sums per col
    int q = lane >> 4, c0 = lane & 15;
    int rbase = row0 + w * 16 + q * 4;
    float sn[4];
    #pragma unroll
    for (int i = 0; i < 4; ++i) sn[i] = (rbase + i < NN) ? snorm[rbase + i] : 0.f;

    float s1[8], s2[8];
    #pragma unroll
    for (int cf = 0; cf < 8; ++cf) {
        s1[cf] = 0.f; s2[cf] = 0.f;
        int col = cf * 16 + c0;
        float bc = bias[col];
        #pragma unroll
        for (int i = 0; i < 4; ++i) {
            int row = rbase + i;
            if (row < NN) {
                float t = (acc[cf][i] + bc) * sn[i];
                t_out[row * DD + col] = f2b(t);
                s1[cf] += t; s2[cf] += t * t;
            }
        }
    }
    #pragma unroll
    for (int cf = 0; cf < 8; ++cf) {
        s1[cf] += __shfl_xor(s1[cf], 16); s1[cf] += __shfl_xor(s1[cf], 32);
        s2[cf] += __shfl_xor(s2[cf], 16); s2[cf] += __shfl_xor(s2[cf], 32);
    }
    if (q == 0) {
        int slot = (blockIdx.x & 31) * DD;
        #pragma unroll
        for (int cf = 0; cf < 8; ++cf) {
            atomAdd(&gsums[slot + cf * 16 + c0], s1[cf]);
            atomAdd(&gsq[slot + cf * 16 + c0], s2[cf]);
        }
    }
}

__global__ void bn_finalize(const float* __restrict__ gsums, const float* __restrict__ gsq,
                            const float* __restrict__ gamma,
                            const float* __restrict__ beta,
                            float* __restrict__ scale, float* __restrict__ shift) {
    int d = threadIdx.x;  // 128
    float s1 = 0.f, s2 = 0.f;
    for (int c = 0; c < 32; ++c) { s1 += gsums[c * DD + d]; s2 += gsq[c * DD + d]; }
    float mean = s1 / (float)NN;
    float var  = s2 / (float)NN - mean * mean;
    float sc = gamma[d] * rsqrtf(var + BN_EPS);
    scale[d] = sc;
    shift[d] = beta[d] - mean * sc;
}

// out = feat + relu(t*scale + shift)   (t is bf16)
__global__ void epilogue(const ushort_t* __restrict__ t, const float* __restrict__ feat,
                         const float* __restrict__ scale, const float* __restrict__ shift,
                         float* __restrict__ out) {
    int i = blockIdx.x * 256 + threadIdx.x;
    if (i >= NN * DD / 4) return;
    int d0 = (i << 2) & 127;
    ushort4 tv = reinterpret_cast<const ushort4*>(t)[i];
    float4 fv = reinterpret_cast<const float4*>(feat)[i];
    float4 o;
    o.x = fv.x + fmaxf(b2f(tv.x) * scale[d0 + 0] + shift[d0 + 0], 0.f);
    o.y = fv.y + fmaxf(b2f(tv.y) * scale[d0 + 1] + shift[d0 + 1], 0.f);
    o.z = fv.z + fmaxf(b2f(tv.z) * scale[d0 + 2] + shift[d0 + 2], 0.f);
    o.w = fv.w + fmaxf(b2f(tv.w) * scale[d0 + 3] + shift[d0 + 3], 0.f);
    reinterpret_cast<float4*>(out)[i] = o;
}

extern "C" void kernel_launch(void* const* d_in, const int* in_sizes, int n_in,
                              void* d_out, int out_size, void* d_ws, size_t ws_size,
                              hipStream_t stream) {
    const float* feat  = (const float*)d_in[0];
    const float* snorm = (const float*)d_in[1];
    const float* W1    = (const float*)d_in[2];
    const float* W2    = (const float*)d_in[3];
    const float* W3    = (const float*)d_in[4];
    const float* bias  = (const float*)d_in[5];
    const float* gamma = (const float*)d_in[6];
    const float* beta  = (const float*)d_in[7];
    const int* esrc = (const int*)d_in[8];
    const int* edst = (const int*)d_in[9];
    float* out = (float*)d_out;

    char* ws = (char*)d_ws;
    ushort_t* t_bf    = (ushort_t*)(ws);                 // 12,800,000
    ushort_t* feat_bf = (ushort_t*)(ws + 12800000);      // 12,800,000
    ushort_t* ax_bf   = (ushort_t*)(ws + 25600000);      // 12,800,000
    ushort_t* ax2_bf  = (ushort_t*)(ws + 38400000);      // 12,800,000
    int*      csrs    = (int*)     (ws + 51200000);      //  3,200,000
    float*    csrn    = (float*)   (ws + 54400000);      //  3,200,000
    float*    norm    = (float*)   (ws + 57600000);      //    200,000
    int*      deg     = (int*)     (ws + 57800000);      //    200,000 (aliased w/ cursor)
    int*      off     = (int*)     (ws + 58000000);      //    200,064
    float*    gsums   = (float*)   (ws + 58200064);      //     16,384
    float*    gsq     = (float*)   (ws + 58216448);      //     16,384
    float*    scale   = (float*)   (ws + 58232832);      //        512
    float*    shift   = (float*)   (ws + 58233344);      //        512  (end 58,233,856)
    ushort_t* wcT     = (ushort_t*)(ws + 58233856);      //     98,304  (end 58,332,160)

    hipMemsetAsync(ws + 57800000, 0, 433856, stream);    // deg, off, gsums, gsq, scale, shift

    deg_kernel <<<3125, 256, 0, stream>>>(edst, deg);
    norm_kernel<<<196,  256, 0, stream>>>(deg, norm);
    scan_kernel<<<1, 1024, 0, stream>>>(deg, off, deg /*cursor alias*/);
    csr_fill   <<<3125, 256, 0, stream>>>(esrc, edst, norm, deg /*cursor*/, csrs, csrn);

    f2bf_kernel<<<6250, 256, 0, stream>>>(feat, feat_bf);
    wct_kernel <<<192,  256, 0, stream>>>(W1, W2, W3, wcT);

    gather_bf<<<12500, 256, 0, stream>>>(feat_bf, norm, off, csrs, csrn, ax_bf);
    gather_bf<<<12500, 256, 0, stream>>>(ax_bf,   norm, off, csrs, csrn, ax2_bf);

    gemm_bn<<<782, 256, 0, stream>>>(feat_bf, ax_bf, ax2_bf, wcT, bias, snorm,
                                     t_bf, gsums, gsq);
    bn_finalize<<<1, 128, 0, stream>>>(gsums, gsq, gamma, beta, scale, shift);
    epilogue   <<<6250, 256, 0, stream>>>(t_bf, feat, scale, shift, out);
}

// Round 5
// 269.205 us; speedup vs baseline: 10.8811x; 1.3658x over previous
//
#include <hip/hip_runtime.h>
#include <hip/hip_bf16.h>

#define NN 50000
#define NE 800000
#define DD 128
#define BN_EPS 1e-5f
#define SCAN_G 98    // 98*512 = 50176 >= NN

typedef unsigned short ushort_t;
typedef unsigned int uint_t;
typedef __attribute__((ext_vector_type(8))) short short8v;   // 8 x bf16 (4 VGPR)
typedef __attribute__((ext_vector_type(4))) float f32x4;

__device__ __forceinline__ float b2f(ushort_t u) {
    union { uint_t i; float f; } v; v.i = ((uint_t)u) << 16; return v.f;
}
__device__ __forceinline__ ushort_t f2b(float f) {
    uint_t u = __float_as_uint(f);
    u += 0x7FFFu + ((u >> 16) & 1u);   // RNE
    return (ushort_t)(u >> 16);
}
__device__ __forceinline__ void atomAdd(float* p, float v) { unsafeAtomicAdd(p, v); }

// ---------- graph prep ----------
__global__ void deg_kernel(const int* __restrict__ dst, int* __restrict__ deg) {
    int e = blockIdx.x * 256 + threadIdx.x;
    if (e < NE) atomicAdd(&deg[dst[e]], 1);
}

__global__ void norm_kernel(const int* __restrict__ deg, float* __restrict__ norm) {
    int i = blockIdx.x * 256 + threadIdx.x;
    if (i < NN) norm[i] = rsqrtf((float)max(deg[i], 1));
}

// hierarchical scan, pass 1: per-block (512 elems) sums
__global__ __launch_bounds__(512) void scan_part(const int* __restrict__ deg,
                                                 int* __restrict__ part) {
    int i = blockIdx.x * 512 + threadIdx.x;
    int v = (i < NN) ? deg[i] : 0;
    #pragma unroll
    for (int s = 1; s < 64; s <<= 1) v += __shfl_xor(v, s);
    __shared__ int wsum[8];
    if ((threadIdx.x & 63) == 0) wsum[threadIdx.x >> 6] = v;
    __syncthreads();
    if (threadIdx.x == 0) {
        int s = 0;
        #pragma unroll
        for (int k = 0; k < 8; ++k) s += wsum[k];
        part[blockIdx.x] = s;
    }
}

// pass 2: exclusive scan of the 98 block sums
__global__ __launch_bounds__(128) void scan_mid(const int* __restrict__ part,
                                                int* __restrict__ base) {
    __shared__ int sh[128];
    int t = threadIdx.x;
    sh[t] = (t < SCAN_G) ? part[t] : 0;
    __syncthreads();
    for (int s = 1; s < 128; s <<= 1) {
        int u = (t >= s) ? sh[t - s] : 0;
        __syncthreads();
        sh[t] += u;
        __syncthreads();
    }
    base[t] = t ? sh[t - 1] : 0;
}

// pass 3: block-local exclusive scan + base -> off, cursor
__global__ __launch_bounds__(512) void scan_final(const int* __restrict__ deg,
                                                  const int* __restrict__ base,
                                                  int* __restrict__ off,
                                                  int* __restrict__ cursor) {
    int i = blockIdx.x * 512 + threadIdx.x;
    int lane = threadIdx.x & 63, wv = threadIdx.x >> 6;
    int v = (i < NN) ? deg[i] : 0;
    int incl = v;
    #pragma unroll
    for (int s = 1; s < 64; s <<= 1) {
        int u = __shfl_up(incl, s);
        if (lane >= s) incl += u;
    }
    __shared__ int wsum[8];
    if (lane == 63) wsum[wv] = incl;
    __syncthreads();
    int woff = 0;
    for (int k = 0; k < wv; ++k) woff += wsum[k];
    int excl = base[blockIdx.x] + woff + incl - v;
    if (i < NN) { off[i] = excl; cursor[i] = excl; }
    if (blockIdx.x == 0 && threadIdx.x == 0) off[NN] = NE;
}

__global__ void csr_fill(const int* __restrict__ src, const int* __restrict__ dst,
                         const float* __restrict__ norm,
                         int* __restrict__ cursor,
                         int* __restrict__ csr_src, float* __restrict__ csr_ns) {
    int e = blockIdx.x * 256 + threadIdx.x;
    if (e >= NE) return;
    int s = src[e];
    int pos = atomicAdd(&cursor[dst[e]], 1);
    csr_src[pos] = s;
    csr_ns[pos] = norm[s];
}

// ---------- conversions ----------
__global__ void f2bf_kernel(const float* __restrict__ in, ushort_t* __restrict__ out) {
    int i = blockIdx.x * 256 + threadIdx.x;   // per 4 elems
    if (i >= NN * DD / 4) return;
    float4 v = reinterpret_cast<const float4*>(in)[i];
    ushort4 o = { f2b(v.x), f2b(v.y), f2b(v.z), f2b(v.w) };
    reinterpret_cast<ushort4*>(out)[i] = o;
}

// WcT[d][k] (128 x 384 bf16): k<128: W1-W3; k<256: -W2; else 2*W3
__global__ void wct_kernel(const float* __restrict__ W1, const float* __restrict__ W2,
                           const float* __restrict__ W3, ushort_t* __restrict__ wcT) {
    int i = blockIdx.x * 256 + threadIdx.x;
    if (i >= DD * 384) return;
    int d = i / 384, k = i % 384;
    float v;
    if (k < 128)      v = W1[k * DD + d] - W3[k * DD + d];
    else if (k < 256) v = -W2[(k - 128) * DD + d];
    else              v = 2.0f * W3[(k - 256) * DD + d];
    wcT[i] = f2b(v);
}

// ---------- message passing (bf16 in, bf16 out) ----------
__global__ __launch_bounds__(256) void gather_bf(const ushort_t* __restrict__ x,
                                                 const float* __restrict__ norm,
                                                 const int* __restrict__ off,
                                                 const int* __restrict__ csr_src,
                                                 const float* __restrict__ csr_ns,
                                                 ushort_t* __restrict__ out) {
    int wid = (blockIdx.x << 2) + (threadIdx.x >> 6);
    int lane = threadIdx.x & 63;
    int jb = off[wid], je = off[wid + 1];
    const uint_t* xp = reinterpret_cast<const uint_t*>(x);
    float ax = 0.f, ay = 0.f;
    int j = jb;
    int s_n = 0; float ns_n = 0.f;
    if (j < je) { s_n = csr_src[j]; ns_n = csr_ns[j]; }
    while (j < je) {
        int s = s_n; float ns = ns_n;
        ++j;
        if (j < je) { s_n = csr_src[j]; ns_n = csr_ns[j]; }
        uint_t v = xp[s * 64 + lane];
        ax = fmaf(ns, b2f((ushort_t)v), ax);
        ay = fmaf(ns, b2f((ushort_t)(v >> 16)), ay);
    }
    float nd = norm[wid];
    uint_t o = (uint_t)f2b(nd * ax) | ((uint_t)f2b(nd * ay) << 16);
    reinterpret_cast<uint_t*>(out)[wid * 64 + lane] = o;
}

// ---------- MFMA GEMM + BN partials ----------
__global__ __launch_bounds__(256) void gemm_bn(
    const ushort_t* __restrict__ feat_bf, const ushort_t* __restrict__ ax_bf,
    const ushort_t* __restrict__ ax2_bf, const ushort_t* __restrict__ wcT,
    const float* __restrict__ bias, const float* __restrict__ snorm,
    ushort_t* __restrict__ t_out, float* __restrict__ gsums, float* __restrict__ gsq)
{
    __shared__ ushort_t As[64 * 128];    // 16 KB, XOR-swizzled
    __shared__ ushort_t Bs[128 * 128];   // 32 KB, XOR-swizzled
    int tid = threadIdx.x;
    int w = tid >> 6, lane = tid & 63;
    int row0 = blockIdx.x * 64;

    f32x4 acc[8] = {};

    #pragma unroll
    for (int kt = 0; kt < 3; ++kt) {
        const ushort_t* S = (kt == 0) ? feat_bf : (kt == 1) ? ax_bf : ax2_bf;
        __syncthreads();
        {
            int r = tid >> 2, q = tid & 3;
            int grow = min(row0 + r, NN - 1);
            const char* gsrc = (const char*)(S + grow * DD);
            char* dbase = (char*)As + r * 256;
            int sw = (r & 7) << 4;
            #pragma unroll
            for (int c = 0; c < 4; ++c) {
                int cb = (q * 4 + c) * 16;
                *(short8v*)(dbase + (cb ^ sw)) = *(const short8v*)(gsrc + cb);
            }
        }
        {
            int cidx = tid >> 1, h = tid & 1;
            const char* gsrc = (const char*)(wcT + cidx * 384 + kt * 128);
            char* dbase = (char*)Bs + cidx * 256;
            int sw = (cidx & 7) << 4;
            #pragma unroll
            for (int c = 0; c < 8; ++c) {
                int cb = (h * 8 + c) * 16;
                *(short8v*)(dbase + (cb ^ sw)) = *(const short8v*)(gsrc + cb);
            }
        }
        __syncthreads();
        int arow = w * 16 + (lane & 15);
        int asw = (arow & 7) << 4;
        #pragma unroll
        for (int ks = 0; ks < 4; ++ks) {
            int kb = ks * 64 + ((lane >> 4) << 4);
            short8v a = *(const short8v*)((const char*)As + arow * 256 + (kb ^ asw));
            #pragma unroll
            for (int cf = 0; cf < 8; ++cf) {
                int col = cf * 16 + (lane & 15);
                short8v b = *(const short8v*)((const char*)Bs + col * 256 + (kb ^ ((col & 7) << 4)));
                acc[cf] = __builtin_amdgcn_mfma_f32_16x16x32_bf16(a, b, acc[cf], 0, 0, 0);
            }
        }
    }

    int q = lane >> 4, c0 = lane & 15;
    int rbase = row0 + w * 16 + q * 4;
    float sn[4];
    #pragma unroll
    for (int i = 0; i < 4; ++i) sn[i] = (rbase + i < NN) ? snorm[rbase + i] : 0.f;

    float s1[8], s2[8];
    #pragma unroll
    for (int cf = 0; cf < 8; ++cf) {
        s1[cf] = 0.f; s2[cf] = 0.f;
        int col = cf * 16 + c0;
        float bc = bias[col];
        #pragma unroll
        for (int i = 0; i < 4; ++i) {
            int row = rbase + i;
            if (row < NN) {
                float t = (acc[cf][i] + bc) * sn[i];
                t_out[row * DD + col] = f2b(t);
                s1[cf] += t; s2[cf] += t * t;
            }
        }
    }
    #pragma unroll
    for (int cf = 0; cf < 8; ++cf) {
        s1[cf] += __shfl_xor(s1[cf], 16); s1[cf] += __shfl_xor(s1[cf], 32);
        s2[cf] += __shfl_xor(s2[cf], 16); s2[cf] += __shfl_xor(s2[cf], 32);
    }
    if (q == 0) {
        int slot = (blockIdx.x & 31) * DD;
        #pragma unroll
        for (int cf = 0; cf < 8; ++cf) {
            atomAdd(&gsums[slot + cf * 16 + c0], s1[cf]);
            atomAdd(&gsq[slot + cf * 16 + c0], s2[cf]);
        }
    }
}

__global__ void bn_finalize(const float* __restrict__ gsums, const float* __restrict__ gsq,
                            const float* __restrict__ gamma,
                            const float* __restrict__ beta,
                            float* __restrict__ scale, float* __restrict__ shift) {
    int d = threadIdx.x;  // 128
    float s1 = 0.f, s2 = 0.f;
    for (int c = 0; c < 32; ++c) { s1 += gsums[c * DD + d]; s2 += gsq[c * DD + d]; }
    float mean = s1 / (float)NN;
    float var  = s2 / (float)NN - mean * mean;
    float sc = gamma[d] * rsqrtf(var + BN_EPS);
    scale[d] = sc;
    shift[d] = beta[d] - mean * sc;
}

// out = feat + relu(t*scale + shift)   (t is bf16)
__global__ void epilogue(const ushort_t* __restrict__ t, const float* __restrict__ feat,
                         const float* __restrict__ scale, const float* __restrict__ shift,
                         float* __restrict__ out) {
    int i = blockIdx.x * 256 + threadIdx.x;
    if (i >= NN * DD / 4) return;
    int d0 = (i << 2) & 127;
    ushort4 tv = reinterpret_cast<const ushort4*>(t)[i];
    float4 fv = reinterpret_cast<const float4*>(feat)[i];
    float4 o;
    o.x = fv.x + fmaxf(b2f(tv.x) * scale[d0 + 0] + shift[d0 + 0], 0.f);
    o.y = fv.y + fmaxf(b2f(tv.y) * scale[d0 + 1] + shift[d0 + 1], 0.f);
    o.z = fv.z + fmaxf(b2f(tv.z) * scale[d0 + 2] + shift[d0 + 2], 0.f);
    o.w = fv.w + fmaxf(b2f(tv.w) * scale[d0 + 3] + shift[d0 + 3], 0.f);
    reinterpret_cast<float4*>(out)[i] = o;
}

extern "C" void kernel_launch(void* const* d_in, const int* in_sizes, int n_in,
                              void* d_out, int out_size, void* d_ws, size_t ws_size,
                              hipStream_t stream) {
    const float* feat  = (const float*)d_in[0];
    const float* snorm = (const float*)d_in[1];
    const float* W1    = (const float*)d_in[2];
    const float* W2    = (const float*)d_in[3];
    const float* W3    = (const float*)d_in[4];
    const float* bias  = (const float*)d_in[5];
    const float* gamma = (const float*)d_in[6];
    const float* beta  = (const float*)d_in[7];
    const int* esrc = (const int*)d_in[8];
    const int* edst = (const int*)d_in[9];
    float* out = (float*)d_out;

    char* ws = (char*)d_ws;
    ushort_t* t_bf    = (ushort_t*)(ws);                 // 12,800,000
    ushort_t* feat_bf = (ushort_t*)(ws + 12800000);      // 12,800,000
    ushort_t* ax_bf   = (ushort_t*)(ws + 25600000);      // 12,800,000
    ushort_t* ax2_bf  = (ushort_t*)(ws + 38400000);      // 12,800,000
    int*      csrs    = (int*)     (ws + 51200000);      //  3,200,000
    float*    csrn    = (float*)   (ws + 54400000);      //  3,200,000
    float*    norm    = (float*)   (ws + 57600000);      //    200,000
    int*      deg     = (int*)     (ws + 57800000);      //    200,000 (aliased w/ cursor)
    float*    gsums   = (float*)   (ws + 58000000);      //     16,384
    float*    gsq     = (float*)   (ws + 58016384);      //     16,384
    int*      off     = (int*)     (ws + 58032768);      //    200,064
    int*      part    = (int*)     (ws + 58232832);      //        512
    int*      base    = (int*)     (ws + 58233344);      //        512
    float*    scale   = (float*)   (ws + 58233856);      //        512
    float*    shift   = (float*)   (ws + 58234368);      //        512
    ushort_t* wcT     = (ushort_t*)(ws + 58234880);      //     98,304 (end 58,333,184)

    hipMemsetAsync(ws + 57800000, 0, 232768, stream);    // deg, gsums, gsq

    deg_kernel <<<3125, 256, 0, stream>>>(edst, deg);
    norm_kernel<<<196,  256, 0, stream>>>(deg, norm);
    scan_part  <<<SCAN_G, 512, 0, stream>>>(deg, part);
    scan_mid   <<<1, 128, 0, stream>>>(part, base);
    scan_final <<<SCAN_G, 512, 0, stream>>>(deg, base, off, deg /*cursor alias*/);
    csr_fill   <<<3125, 256, 0, stream>>>(esrc, edst, norm, deg /*cursor*/, csrs, csrn);

    f2bf_kernel<<<6250, 256, 0, stream>>>(feat, feat_bf);
    wct_kernel <<<192,  256, 0, stream>>>(W1, W2, W3, wcT);

    gather_bf<<<12500, 256, 0, stream>>>(feat_bf, norm, off, csrs, csrn, ax_bf);
    gather_bf<<<12500, 256, 0, stream>>>(ax_bf,   norm, off, csrs, csrn, ax2_bf);

    gemm_bn<<<782, 256, 0, stream>>>(feat_bf, ax_bf, ax2_bf, wcT, bias, snorm,
                                     t_bf, gsums, gsq);
    bn_finalize<<<1, 128, 0, stream>>>(gsums, gsq, gamma, beta, scale, shift);
    epilogue   <<<6250, 256, 0, stream>>>(t_bf, feat, scale, shift, out);
}

// Round 6
// 231.569 us; speedup vs baseline: 12.6496x; 1.1625x over previous
//
#include <hip/hip_runtime.h>
#include <hip/hip_bf16.h>

#define NN 50000
#define NE 800000
#define DD 128
#define BN_EPS 1e-5f
#define SCAN_G 98    // 98*512 = 50176 >= NN

typedef unsigned short ushort_t;
typedef unsigned int uint_t;
typedef __attribute__((ext_vector_type(8))) short short8v;   // 8 x bf16 (4 VGPR)
typedef __attribute__((ext_vector_type(4))) float f32x4;

__device__ __forceinline__ float b2f(ushort_t u) {
    union { uint_t i; float f; } v; v.i = ((uint_t)u) << 16; return v.f;
}
__device__ __forceinline__ ushort_t f2b(float f) {
    uint_t u = __float_as_uint(f);
    u += 0x7FFFu + ((u >> 16) & 1u);   // RNE
    return (ushort_t)(u >> 16);
}
__device__ __forceinline__ void atomAdd(float* p, float v) { unsafeAtomicAdd(p, v); }

// ---------- graph prep ----------
__global__ void deg_kernel(const int* __restrict__ dst, int* __restrict__ deg) {
    int e = blockIdx.x * 256 + threadIdx.x;
    if (e < NE) atomicAdd(&deg[dst[e]], 1);
}

__global__ void norm_kernel(const int* __restrict__ deg, float* __restrict__ norm) {
    int i = blockIdx.x * 256 + threadIdx.x;
    if (i < NN) norm[i] = rsqrtf((float)max(deg[i], 1));
}

// hierarchical scan, pass 1: per-block (512 elems) sums
__global__ __launch_bounds__(512) void scan_part(const int* __restrict__ deg,
                                                 int* __restrict__ part) {
    int i = blockIdx.x * 512 + threadIdx.x;
    int v = (i < NN) ? deg[i] : 0;
    #pragma unroll
    for (int s = 1; s < 64; s <<= 1) v += __shfl_xor(v, s);
    __shared__ int wsum[8];
    if ((threadIdx.x & 63) == 0) wsum[threadIdx.x >> 6] = v;
    __syncthreads();
    if (threadIdx.x == 0) {
        int s = 0;
        #pragma unroll
        for (int k = 0; k < 8; ++k) s += wsum[k];
        part[blockIdx.x] = s;
    }
}

// pass 2: exclusive scan of the 98 block sums
__global__ __launch_bounds__(128) void scan_mid(const int* __restrict__ part,
                                                int* __restrict__ base) {
    __shared__ int sh[128];
    int t = threadIdx.x;
    sh[t] = (t < SCAN_G) ? part[t] : 0;
    __syncthreads();
    for (int s = 1; s < 128; s <<= 1) {
        int u = (t >= s) ? sh[t - s] : 0;
        __syncthreads();
        sh[t] += u;
        __syncthreads();
    }
    base[t] = t ? sh[t - 1] : 0;
}

// pass 3: block-local exclusive scan + base -> off, cursor
__global__ __launch_bounds__(512) void scan_final(const int* __restrict__ deg,
                                                  const int* __restrict__ base,
                                                  int* __restrict__ off,
                                                  int* __restrict__ cursor) {
    int i = blockIdx.x * 512 + threadIdx.x;
    int lane = threadIdx.x & 63, wv = threadIdx.x >> 6;
    int v = (i < NN) ? deg[i] : 0;
    int incl = v;
    #pragma unroll
    for (int s = 1; s < 64; s <<= 1) {
        int u = __shfl_up(incl, s);
        if (lane >= s) incl += u;
    }
    __shared__ int wsum[8];
    if (lane == 63) wsum[wv] = incl;
    __syncthreads();
    int woff = 0;
    for (int k = 0; k < wv; ++k) woff += wsum[k];
    int excl = base[blockIdx.x] + woff + incl - v;
    if (i < NN) { off[i] = excl; cursor[i] = excl; }
    if (blockIdx.x == 0 && threadIdx.x == 0) off[NN] = NE;
}

// bucket edges by dst: csr[pos] = (src, bits(norm[src]))
__global__ void csr_fill(const int* __restrict__ src, const int* __restrict__ dst,
                         const float* __restrict__ norm,
                         int* __restrict__ cursor,
                         int2* __restrict__ csr) {
    int e = blockIdx.x * 256 + threadIdx.x;
    if (e >= NE) return;
    int s = src[e];
    int pos = atomicAdd(&cursor[dst[e]], 1);
    csr[pos] = make_int2(s, __float_as_int(norm[s]));
}

// ---------- conversions ----------
__global__ void f2bf_kernel(const float* __restrict__ in, ushort_t* __restrict__ out) {
    int i = blockIdx.x * 256 + threadIdx.x;   // per 4 elems
    if (i >= NN * DD / 4) return;
    float4 v = reinterpret_cast<const float4*>(in)[i];
    ushort4 o = { f2b(v.x), f2b(v.y), f2b(v.z), f2b(v.w) };
    reinterpret_cast<ushort4*>(out)[i] = o;
}

// WcT[d][k] (128 x 384 bf16): k<128: W1-W3; k<256: -W2; else 2*W3
__global__ void wct_kernel(const float* __restrict__ W1, const float* __restrict__ W2,
                           const float* __restrict__ W3, ushort_t* __restrict__ wcT) {
    int i = blockIdx.x * 256 + threadIdx.x;
    if (i >= DD * 384) return;
    int d = i / 384, k = i % 384;
    float v;
    if (k < 128)      v = W1[k * DD + d] - W3[k * DD + d];
    else if (k < 256) v = -W2[(k - 128) * DD + d];
    else              v = 2.0f * W3[(k - 256) * DD + d];
    wcT[i] = f2b(v);
}

// ---------- message passing (bf16 in, bf16 out) ----------
// out[d,:] = bf16( norm[d] * sum_e norm[src_e] * x[src_e,:] ); wave per node.
// 4-way unrolled: 4 independent 256B row loads in flight per wave.
__global__ __launch_bounds__(256) void gather_bf(const ushort_t* __restrict__ x,
                                                 const float* __restrict__ norm,
                                                 const int* __restrict__ off,
                                                 const int2* __restrict__ csr,
                                                 ushort_t* __restrict__ out) {
    int wid = (blockIdx.x << 2) + (threadIdx.x >> 6);
    int lane = threadIdx.x & 63;
    int jb = off[wid], je = off[wid + 1];
    const uint_t* xp = reinterpret_cast<const uint_t*>(x);
    float ax = 0.f, ay = 0.f;
    int j = jb;
    for (; j + 4 <= je; j += 4) {
        int2 c0 = csr[j + 0];
        int2 c1 = csr[j + 1];
        int2 c2 = csr[j + 2];
        int2 c3 = csr[j + 3];
        uint_t v0 = xp[c0.x * 64 + lane];
        uint_t v1 = xp[c1.x * 64 + lane];
        uint_t v2 = xp[c2.x * 64 + lane];
        uint_t v3 = xp[c3.x * 64 + lane];
        float n0 = __int_as_float(c0.y), n1 = __int_as_float(c1.y);
        float n2 = __int_as_float(c2.y), n3 = __int_as_float(c3.y);
        ax = fmaf(n0, b2f((ushort_t)v0), ax);
        ay = fmaf(n0, b2f((ushort_t)(v0 >> 16)), ay);
        ax = fmaf(n1, b2f((ushort_t)v1), ax);
        ay = fmaf(n1, b2f((ushort_t)(v1 >> 16)), ay);
        ax = fmaf(n2, b2f((ushort_t)v2), ax);
        ay = fmaf(n2, b2f((ushort_t)(v2 >> 16)), ay);
        ax = fmaf(n3, b2f((ushort_t)v3), ax);
        ay = fmaf(n3, b2f((ushort_t)(v3 >> 16)), ay);
    }
    for (; j < je; ++j) {
        int2 c = csr[j];
        uint_t v = xp[c.x * 64 + lane];
        float ns = __int_as_float(c.y);
        ax = fmaf(ns, b2f((ushort_t)v), ax);
        ay = fmaf(ns, b2f((ushort_t)(v >> 16)), ay);
    }
    float nd = norm[wid];
    uint_t o = (uint_t)f2b(nd * ax) | ((uint_t)f2b(nd * ay) << 16);
    reinterpret_cast<uint_t*>(out)[wid * 64 + lane] = o;
}

// ---------- MFMA GEMM + BN partials ----------
__global__ __launch_bounds__(256) void gemm_bn(
    const ushort_t* __restrict__ feat_bf, const ushort_t* __restrict__ ax_bf,
    const ushort_t* __restrict__ ax2_bf, const ushort_t* __restrict__ wcT,
    const float* __restrict__ bias, const float* __restrict__ snorm,
    ushort_t* __restrict__ t_out, float* __restrict__ gsums, float* __restrict__ gsq)
{
    __shared__ ushort_t As[64 * 128];    // 16 KB, XOR-swizzled
    __shared__ ushort_t Bs[128 * 128];   // 32 KB, XOR-swizzled
    int tid = threadIdx.x;
    int w = tid >> 6, lane = tid & 63;
    int row0 = blockIdx.x * 64;

    f32x4 acc[8] = {};

    #pragma unroll
    for (int kt = 0; kt < 3; ++kt) {
        const ushort_t* S = (kt == 0) ? feat_bf : (kt == 1) ? ax_bf : ax2_bf;
        __syncthreads();
        {
            int r = tid >> 2, q = tid & 3;
            int grow = min(row0 + r, NN - 1);
            const char* gsrc = (const char*)(S + grow * DD);
            char* dbase = (char*)As + r * 256;
            int sw = (r & 7) << 4;
            #pragma unroll
            for (int c = 0; c < 4; ++c) {
                int cb = (q * 4 + c) * 16;
                *(short8v*)(dbase + (cb ^ sw)) = *(const short8v*)(gsrc + cb);
            }
        }
        {
            int cidx = tid >> 1, h = tid & 1;
            const char* gsrc = (const char*)(wcT + cidx * 384 + kt * 128);
            char* dbase = (char*)Bs + cidx * 256;
            int sw = (cidx & 7) << 4;
            #pragma unroll
            for (int c = 0; c < 8; ++c) {
                int cb = (h * 8 + c) * 16;
                *(short8v*)(dbase + (cb ^ sw)) = *(const short8v*)(gsrc + cb);
            }
        }
        __syncthreads();
        int arow = w * 16 + (lane & 15);
        int asw = (arow & 7) << 4;
        #pragma unroll
        for (int ks = 0; ks < 4; ++ks) {
            int kb = ks * 64 + ((lane >> 4) << 4);
            short8v a = *(const short8v*)((const char*)As + arow * 256 + (kb ^ asw));
            #pragma unroll
            for (int cf = 0; cf < 8; ++cf) {
                int col = cf * 16 + (lane & 15);
                short8v b = *(const short8v*)((const char*)Bs + col * 256 + (kb ^ ((col & 7) << 4)));
                acc[cf] = __builtin_amdgcn_mfma_f32_16x16x32_bf16(a, b, acc[cf], 0, 0, 0);
            }
        }
    }

    int q = lane >> 4, c0 = lane & 15;
    int rbase = row0 + w * 16 + q * 4;
    float sn[4];
    #pragma unroll
    for (int i = 0; i < 4; ++i) sn[i] = (rbase + i < NN) ? snorm[rbase + i] : 0.f;

    float s1[8], s2[8];
    #pragma unroll
    for (int cf = 0; cf < 8; ++cf) {
        s1[cf] = 0.f; s2[cf] = 0.f;
        int col = cf * 16 + c0;
        float bc = bias[col];
        #pragma unroll
        for (int i = 0; i < 4; ++i) {
            int row = rbase + i;
            if (row < NN) {
                float t = (acc[cf][i] + bc) * sn[i];
                t_out[row * DD + col] = f2b(t);
                s1[cf] += t; s2[cf] += t * t;
            }
        }
    }
    #pragma unroll
    for (int cf = 0; cf < 8; ++cf) {
        s1[cf] += __shfl_xor(s1[cf], 16); s1[cf] += __shfl_xor(s1[cf], 32);
        s2[cf] += __shfl_xor(s2[cf], 16); s2[cf] += __shfl_xor(s2[cf], 32);
    }
    if (q == 0) {
        int slot = (blockIdx.x & 31) * DD;
        #pragma unroll
        for (int cf = 0; cf < 8; ++cf) {
            atomAdd(&gsums[slot + cf * 16 + c0], s1[cf]);
            atomAdd(&gsq[slot + cf * 16 + c0], s2[cf]);
        }
    }
}

__global__ void bn_finalize(const float* __restrict__ gsums, const float* __restrict__ gsq,
                            const float* __restrict__ gamma,
                            const float* __restrict__ beta,
                            float* __restrict__ scale, float* __restrict__ shift) {
    int d = threadIdx.x;  // 128
    float s1 = 0.f, s2 = 0.f;
    for (int c = 0; c < 32; ++c) { s1 += gsums[c * DD + d]; s2 += gsq[c * DD + d]; }
    float mean = s1 / (float)NN;
    float var  = s2 / (float)NN - mean * mean;
    float sc = gamma[d] * rsqrtf(var + BN_EPS);
    scale[d] = sc;
    shift[d] = beta[d] - mean * sc;
}

// out = feat + relu(t*scale + shift)   (t is bf16)
__global__ void epilogue(const ushort_t* __restrict__ t, const float* __restrict__ feat,
                         const float* __restrict__ scale, const float* __restrict__ shift,
                         float* __restrict__ out) {
    int i = blockIdx.x * 256 + threadIdx.x;
    if (i >= NN * DD / 4) return;
    int d0 = (i << 2) & 127;
    ushort4 tv = reinterpret_cast<const ushort4*>(t)[i];
    float4 fv = reinterpret_cast<const float4*>(feat)[i];
    float4 o;
    o.x = fv.x + fmaxf(b2f(tv.x) * scale[d0 + 0] + shift[d0 + 0], 0.f);
    o.y = fv.y + fmaxf(b2f(tv.y) * scale[d0 + 1] + shift[d0 + 1], 0.f);
    o.z = fv.z + fmaxf(b2f(tv.z) * scale[d0 + 2] + shift[d0 + 2], 0.f);
    o.w = fv.w + fmaxf(b2f(tv.w) * scale[d0 + 3] + shift[d0 + 3], 0.f);
    reinterpret_cast<float4*>(out)[i] = o;
}

extern "C" void kernel_launch(void* const* d_in, const int* in_sizes, int n_in,
                              void* d_out, int out_size, void* d_ws, size_t ws_size,
                              hipStream_t stream) {
    const float* feat  = (const float*)d_in[0];
    const float* snorm = (const float*)d_in[1];
    const float* W1    = (const float*)d_in[2];
    const float* W2    = (const float*)d_in[3];
    const float* W3    = (const float*)d_in[4];
    const float* bias  = (const float*)d_in[5];
    const float* gamma = (const float*)d_in[6];
    const float* beta  = (const float*)d_in[7];
    const int* esrc = (const int*)d_in[8];
    const int* edst = (const int*)d_in[9];
    float* out = (float*)d_out;

    char* ws = (char*)d_ws;
    ushort_t* t_bf    = (ushort_t*)(ws);                 // 12,800,000
    ushort_t* feat_bf = (ushort_t*)(ws + 12800000);      // 12,800,000
    ushort_t* ax_bf   = (ushort_t*)(ws + 25600000);      // 12,800,000
    ushort_t* ax2_bf  = (ushort_t*)(ws + 38400000);      // 12,800,000
    int2*     csr     = (int2*)    (ws + 51200000);      //  6,400,000 (src, norm bits)
    float*    norm    = (float*)   (ws + 57600000);      //    200,000
    int*      deg     = (int*)     (ws + 57800000);      //    200,000 (aliased w/ cursor)
    float*    gsums   = (float*)   (ws + 58000000);      //     16,384
    float*    gsq     = (float*)   (ws + 58016384);      //     16,384
    int*      off     = (int*)     (ws + 58032768);      //    200,064
    int*      part    = (int*)     (ws + 58232832);      //        512
    int*      base    = (int*)     (ws + 58233344);      //        512
    float*    scale   = (float*)   (ws + 58233856);      //        512
    float*    shift   = (float*)   (ws + 58234368);      //        512
    ushort_t* wcT     = (ushort_t*)(ws + 58234880);      //     98,304 (end 58,333,184)

    hipMemsetAsync(ws + 57800000, 0, 232768, stream);    // deg, gsums, gsq

    deg_kernel <<<3125, 256, 0, stream>>>(edst, deg);
    norm_kernel<<<196,  256, 0, stream>>>(deg, norm);
    scan_part  <<<SCAN_G, 512, 0, stream>>>(deg, part);
    scan_mid   <<<1, 128, 0, stream>>>(part, base);
    scan_final <<<SCAN_G, 512, 0, stream>>>(deg, base, off, deg /*cursor alias*/);
    csr_fill   <<<3125, 256, 0, stream>>>(esrc, edst, norm, deg /*cursor*/, csr);

    f2bf_kernel<<<6250, 256, 0, stream>>>(feat, feat_bf);
    wct_kernel <<<192,  256, 0, stream>>>(W1, W2, W3, wcT);

    gather_bf<<<12500, 256, 0, stream>>>(feat_bf, norm, off, csr, ax_bf);
    gather_bf<<<12500, 256, 0, stream>>>(ax_bf,   norm, off, csr, ax2_bf);

    gemm_bn<<<782, 256, 0, stream>>>(feat_bf, ax_bf, ax2_bf, wcT, bias, snorm,
                                     t_bf, gsums, gsq);
    bn_finalize<<<1, 128, 0, stream>>>(gsums, gsq, gamma, beta, scale, shift);
    epilogue   <<<6250, 256, 0, stream>>>(t_bf, feat, scale, shift, out);
}

// Round 7
// 197.560 us; speedup vs baseline: 14.8271x; 1.1721x over previous
//
#include <hip/hip_runtime.h>
#include <hip/hip_bf16.h>

#define NN 50000
#define NE 800000
#define DD 128
#define BN_EPS 1e-5f
#define SCAN_G 98    // 98*512 = 50176 >= NN

typedef unsigned short ushort_t;
typedef unsigned int uint_t;
typedef __attribute__((ext_vector_type(8))) short short8v;   // 8 x bf16 (4 VGPR)
typedef __attribute__((ext_vector_type(4))) float f32x4;

__device__ __forceinline__ float b2f(ushort_t u) {
    union { uint_t i; float f; } v; v.i = ((uint_t)u) << 16; return v.f;
}
__device__ __forceinline__ ushort_t f2b(float f) {
    uint_t u = __float_as_uint(f);
    u += 0x7FFFu + ((u >> 16) & 1u);   // RNE
    return (ushort_t)(u >> 16);
}
__device__ __forceinline__ void atomAdd(float* p, float v) { unsafeAtomicAdd(p, v); }

// ---------- graph prep ----------
// epos[e] = position of edge e within its dst bucket; cnt ends as deg.
__global__ void epos_kernel(const int* __restrict__ dst, int* __restrict__ cnt,
                            int* __restrict__ epos) {
    int e = blockIdx.x * 256 + threadIdx.x;
    if (e < NE) epos[e] = atomicAdd(&cnt[dst[e]], 1);
}

__global__ void norm_kernel(const int* __restrict__ deg, float* __restrict__ norm) {
    int i = blockIdx.x * 256 + threadIdx.x;
    if (i < NN) norm[i] = rsqrtf((float)max(deg[i], 1));
}

// hierarchical scan, pass 1: per-block (512 elems) sums
__global__ __launch_bounds__(512) void scan_part(const int* __restrict__ deg,
                                                 int* __restrict__ part) {
    int i = blockIdx.x * 512 + threadIdx.x;
    int v = (i < NN) ? deg[i] : 0;
    #pragma unroll
    for (int s = 1; s < 64; s <<= 1) v += __shfl_xor(v, s);
    __shared__ int wsum[8];
    if ((threadIdx.x & 63) == 0) wsum[threadIdx.x >> 6] = v;
    __syncthreads();
    if (threadIdx.x == 0) {
        int s = 0;
        #pragma unroll
        for (int k = 0; k < 8; ++k) s += wsum[k];
        part[blockIdx.x] = s;
    }
}

// pass 2: exclusive scan of the 98 block sums
__global__ __launch_bounds__(128) void scan_mid(const int* __restrict__ part,
                                                int* __restrict__ base) {
    __shared__ int sh[128];
    int t = threadIdx.x;
    sh[t] = (t < SCAN_G) ? part[t] : 0;
    __syncthreads();
    for (int s = 1; s < 128; s <<= 1) {
        int u = (t >= s) ? sh[t - s] : 0;
        __syncthreads();
        sh[t] += u;
        __syncthreads();
    }
    base[t] = t ? sh[t - 1] : 0;
}

// pass 3: block-local exclusive scan + base -> off
__global__ __launch_bounds__(512) void scan_final(const int* __restrict__ deg,
                                                  const int* __restrict__ base,
                                                  int* __restrict__ off) {
    int i = blockIdx.x * 512 + threadIdx.x;
    int lane = threadIdx.x & 63, wv = threadIdx.x >> 6;
    int v = (i < NN) ? deg[i] : 0;
    int incl = v;
    #pragma unroll
    for (int s = 1; s < 64; s <<= 1) {
        int u = __shfl_up(incl, s);
        if (lane >= s) incl += u;
    }
    __shared__ int wsum[8];
    if (lane == 63) wsum[wv] = incl;
    __syncthreads();
    int woff = 0;
    for (int k = 0; k < wv; ++k) woff += wsum[k];
    int excl = base[blockIdx.x] + woff + incl - v;
    if (i < NN) off[i] = excl;
    if (blockIdx.x == 0 && threadIdx.x == 0) off[NN] = NE;
}

// csr[off[dst]+epos] = (src, bits(norm[src])) — atomic-free scatter
__global__ void fill_kernel(const int* __restrict__ src, const int* __restrict__ dst,
                            const int* __restrict__ epos, const int* __restrict__ off,
                            const float* __restrict__ norm, int2* __restrict__ csr) {
    int e = blockIdx.x * 256 + threadIdx.x;
    if (e >= NE) return;
    int s = src[e];
    int p = off[dst[e]] + epos[e];
    csr[p] = make_int2(s, __float_as_int(norm[s]));
}

// ---------- conversions ----------
__global__ void f2bf_kernel(const float* __restrict__ in, ushort_t* __restrict__ out) {
    int i = blockIdx.x * 256 + threadIdx.x;   // per 4 elems
    if (i >= NN * DD / 4) return;
    float4 v = reinterpret_cast<const float4*>(in)[i];
    ushort4 o = { f2b(v.x), f2b(v.y), f2b(v.z), f2b(v.w) };
    reinterpret_cast<ushort4*>(out)[i] = o;
}

// WcT[d][k] (128 x 384 bf16): k<128: W1-W3; k<256: -W2; else 2*W3
__global__ void wct_kernel(const float* __restrict__ W1, const float* __restrict__ W2,
                           const float* __restrict__ W3, ushort_t* __restrict__ wcT) {
    int i = blockIdx.x * 256 + threadIdx.x;
    if (i >= DD * 384) return;
    int d = i / 384, k = i % 384;
    float v;
    if (k < 128)      v = W1[k * DD + d] - W3[k * DD + d];
    else if (k < 256) v = -W2[(k - 128) * DD + d];
    else              v = 2.0f * W3[(k - 256) * DD + d];
    wcT[i] = f2b(v);
}

// ---------- message passing (bf16 in, bf16 out) ----------
// out[d,:] = bf16( norm[d] * sum_e norm[src_e] * x[src_e,:] ); wave per node.
// 4-way unrolled: 4 independent 256B row loads in flight per wave.
__global__ __launch_bounds__(256) void gather_bf(const ushort_t* __restrict__ x,
                                                 const float* __restrict__ norm,
                                                 const int* __restrict__ off,
                                                 const int2* __restrict__ csr,
                                                 ushort_t* __restrict__ out) {
    int wid = (blockIdx.x << 2) + (threadIdx.x >> 6);
    int lane = threadIdx.x & 63;
    int jb = off[wid], je = off[wid + 1];
    const uint_t* xp = reinterpret_cast<const uint_t*>(x);
    float ax = 0.f, ay = 0.f;
    int j = jb;
    for (; j + 4 <= je; j += 4) {
        int2 c0 = csr[j + 0];
        int2 c1 = csr[j + 1];
        int2 c2 = csr[j + 2];
        int2 c3 = csr[j + 3];
        uint_t v0 = xp[c0.x * 64 + lane];
        uint_t v1 = xp[c1.x * 64 + lane];
        uint_t v2 = xp[c2.x * 64 + lane];
        uint_t v3 = xp[c3.x * 64 + lane];
        float n0 = __int_as_float(c0.y), n1 = __int_as_float(c1.y);
        float n2 = __int_as_float(c2.y), n3 = __int_as_float(c3.y);
        ax = fmaf(n0, b2f((ushort_t)v0), ax);
        ay = fmaf(n0, b2f((ushort_t)(v0 >> 16)), ay);
        ax = fmaf(n1, b2f((ushort_t)v1), ax);
        ay = fmaf(n1, b2f((ushort_t)(v1 >> 16)), ay);
        ax = fmaf(n2, b2f((ushort_t)v2), ax);
        ay = fmaf(n2, b2f((ushort_t)(v2 >> 16)), ay);
        ax = fmaf(n3, b2f((ushort_t)v3), ax);
        ay = fmaf(n3, b2f((ushort_t)(v3 >> 16)), ay);
    }
    for (; j < je; ++j) {
        int2 c = csr[j];
        uint_t v = xp[c.x * 64 + lane];
        float ns = __int_as_float(c.y);
        ax = fmaf(ns, b2f((ushort_t)v), ax);
        ay = fmaf(ns, b2f((ushort_t)(v >> 16)), ay);
    }
    float nd = norm[wid];
    uint_t o = (uint_t)f2b(nd * ax) | ((uint_t)f2b(nd * ay) << 16);
    reinterpret_cast<uint_t*>(out)[wid * 64 + lane] = o;
}

// ---------- MFMA GEMM + BN partials ----------
__global__ __launch_bounds__(256) void gemm_bn(
    const ushort_t* __restrict__ feat_bf, const ushort_t* __restrict__ ax_bf,
    const ushort_t* __restrict__ ax2_bf, const ushort_t* __restrict__ wcT,
    const float* __restrict__ bias, const float* __restrict__ snorm,
    ushort_t* __restrict__ t_out, float* __restrict__ gsums, float* __restrict__ gsq)
{
    __shared__ ushort_t As[64 * 128];    // 16 KB, XOR-swizzled
    __shared__ ushort_t Bs[128 * 128];   // 32 KB, XOR-swizzled
    int tid = threadIdx.x;
    int w = tid >> 6, lane = tid & 63;
    int row0 = blockIdx.x * 64;

    f32x4 acc[8] = {};

    #pragma unroll
    for (int kt = 0; kt < 3; ++kt) {
        const ushort_t* S = (kt == 0) ? feat_bf : (kt == 1) ? ax_bf : ax2_bf;
        __syncthreads();
        {
            int r = tid >> 2, q = tid & 3;
            int grow = min(row0 + r, NN - 1);
            const char* gsrc = (const char*)(S + grow * DD);
            char* dbase = (char*)As + r * 256;
            int sw = (r & 7) << 4;
            #pragma unroll
            for (int c = 0; c < 4; ++c) {
                int cb = (q * 4 + c) * 16;
                *(short8v*)(dbase + (cb ^ sw)) = *(const short8v*)(gsrc + cb);
            }
        }
        {
            int cidx = tid >> 1, h = tid & 1;
            const char* gsrc = (const char*)(wcT + cidx * 384 + kt * 128);
            char* dbase = (char*)Bs + cidx * 256;
            int sw = (cidx & 7) << 4;
            #pragma unroll
            for (int c = 0; c < 8; ++c) {
                int cb = (h * 8 + c) * 16;
                *(short8v*)(dbase + (cb ^ sw)) = *(const short8v*)(gsrc + cb);
            }
        }
        __syncthreads();
        int arow = w * 16 + (lane & 15);
        int asw = (arow & 7) << 4;
        #pragma unroll
        for (int ks = 0; ks < 4; ++ks) {
            int kb = ks * 64 + ((lane >> 4) << 4);
            short8v a = *(const short8v*)((const char*)As + arow * 256 + (kb ^ asw));
            #pragma unroll
            for (int cf = 0; cf < 8; ++cf) {
                int col = cf * 16 + (lane & 15);
                short8v b = *(const short8v*)((const char*)Bs + col * 256 + (kb ^ ((col & 7) << 4)));
                acc[cf] = __builtin_amdgcn_mfma_f32_16x16x32_bf16(a, b, acc[cf], 0, 0, 0);
            }
        }
    }

    int q = lane >> 4, c0 = lane & 15;
    int rbase = row0 + w * 16 + q * 4;
    float sn[4];
    #pragma unroll
    for (int i = 0; i < 4; ++i) sn[i] = (rbase + i < NN) ? snorm[rbase + i] : 0.f;

    float s1[8], s2[8];
    #pragma unroll
    for (int cf = 0; cf < 8; ++cf) {
        s1[cf] = 0.f; s2[cf] = 0.f;
        int col = cf * 16 + c0;
        float bc = bias[col];
        #pragma unroll
        for (int i = 0; i < 4; ++i) {
            int row = rbase + i;
            if (row < NN) {
                float t = (acc[cf][i] + bc) * sn[i];
                t_out[row * DD + col] = f2b(t);
                s1[cf] += t; s2[cf] += t * t;
            }
        }
    }
    #pragma unroll
    for (int cf = 0; cf < 8; ++cf) {
        s1[cf] += __shfl_xor(s1[cf], 16); s1[cf] += __shfl_xor(s1[cf], 32);
        s2[cf] += __shfl_xor(s2[cf], 16); s2[cf] += __shfl_xor(s2[cf], 32);
    }
    if (q == 0) {
        int slot = (blockIdx.x & 31) * DD;
        #pragma unroll
        for (int cf = 0; cf < 8; ++cf) {
            atomAdd(&gsums[slot + cf * 16 + c0], s1[cf]);
            atomAdd(&gsq[slot + cf * 16 + c0], s2[cf]);
        }
    }
}

__global__ void bn_finalize(const float* __restrict__ gsums, const float* __restrict__ gsq,
                            const float* __restrict__ gamma,
                            const float* __restrict__ beta,
                            float* __restrict__ scale, float* __restrict__ shift) {
    int d = threadIdx.x;  // 128
    float s1 = 0.f, s2 = 0.f;
    for (int c = 0; c < 32; ++c) { s1 += gsums[c * DD + d]; s2 += gsq[c * DD + d]; }
    float mean = s1 / (float)NN;
    float var  = s2 / (float)NN - mean * mean;
    float sc = gamma[d] * rsqrtf(var + BN_EPS);
    scale[d] = sc;
    shift[d] = beta[d] - mean * sc;
}

// out = feat + relu(t*scale + shift)   (t is bf16)
__global__ void epilogue(const ushort_t* __restrict__ t, const float* __restrict__ feat,
                         const float* __restrict__ scale, const float* __restrict__ shift,
                         float* __restrict__ out) {
    int i = blockIdx.x * 256 + threadIdx.x;
    if (i >= NN * DD / 4) return;
    int d0 = (i << 2) & 127;
    ushort4 tv = reinterpret_cast<const ushort4*>(t)[i];
    float4 fv = reinterpret_cast<const float4*>(feat)[i];
    float4 o;
    o.x = fv.x + fmaxf(b2f(tv.x) * scale[d0 + 0] + shift[d0 + 0], 0.f);
    o.y = fv.y + fmaxf(b2f(tv.y) * scale[d0 + 1] + shift[d0 + 1], 0.f);
    o.z = fv.z + fmaxf(b2f(tv.z) * scale[d0 + 2] + shift[d0 + 2], 0.f);
    o.w = fv.w + fmaxf(b2f(tv.w) * scale[d0 + 3] + shift[d0 + 3], 0.f);
    reinterpret_cast<float4*>(out)[i] = o;
}

extern "C" void kernel_launch(void* const* d_in, const int* in_sizes, int n_in,
                              void* d_out, int out_size, void* d_ws, size_t ws_size,
                              hipStream_t stream) {
    const float* feat  = (const float*)d_in[0];
    const float* snorm = (const float*)d_in[1];
    const float* W1    = (const float*)d_in[2];
    const float* W2    = (const float*)d_in[3];
    const float* W3    = (const float*)d_in[4];
    const float* bias  = (const float*)d_in[5];
    const float* gamma = (const float*)d_in[6];
    const float* beta  = (const float*)d_in[7];
    const int* esrc = (const int*)d_in[8];
    const int* edst = (const int*)d_in[9];
    float* out = (float*)d_out;

    char* ws = (char*)d_ws;
    ushort_t* t_bf    = (ushort_t*)(ws);                 // 12,800,000 (gemm output)
    int*      epos    = (int*)     (ws);                 //  3,200,000 ALIAS of t_bf
                                                         //  (epos dead before gemm_bn runs)
    ushort_t* feat_bf = (ushort_t*)(ws + 12800000);      // 12,800,000
    ushort_t* ax_bf   = (ushort_t*)(ws + 25600000);      // 12,800,000
    ushort_t* ax2_bf  = (ushort_t*)(ws + 38400000);      // 12,800,000
    int2*     csr     = (int2*)    (ws + 51200000);      //  6,400,000 (src, norm bits)
    float*    norm    = (float*)   (ws + 57600000);      //    200,000
    int*      cnt     = (int*)     (ws + 57800000);      //    200,000 (-> deg)
    float*    gsums   = (float*)   (ws + 58000000);      //     16,384
    float*    gsq     = (float*)   (ws + 58016384);      //     16,384
    int*      off     = (int*)     (ws + 58032768);      //    200,064
    int*      part    = (int*)     (ws + 58232832);      //        512
    int*      base    = (int*)     (ws + 58233344);      //        512
    float*    scale   = (float*)   (ws + 58233856);      //        512
    float*    shift   = (float*)   (ws + 58234368);      //        512
    ushort_t* wcT     = (ushort_t*)(ws + 58234880);      //     98,304 (end 58,333,184)

    hipMemsetAsync(ws + 57800000, 0, 232768, stream);    // cnt, gsums, gsq

    epos_kernel<<<3125, 256, 0, stream>>>(edst, cnt, epos);
    norm_kernel<<<196,  256, 0, stream>>>(cnt, norm);
    scan_part  <<<SCAN_G, 512, 0, stream>>>(cnt, part);
    scan_mid   <<<1, 128, 0, stream>>>(part, base);
    scan_final <<<SCAN_G, 512, 0, stream>>>(cnt, base, off);
    fill_kernel<<<3125, 256, 0, stream>>>(esrc, edst, epos, off, norm, csr);

    f2bf_kernel<<<6250, 256, 0, stream>>>(feat, feat_bf);
    wct_kernel <<<192,  256, 0, stream>>>(W1, W2, W3, wcT);

    gather_bf<<<12500, 256, 0, stream>>>(feat_bf, norm, off, csr, ax_bf);
    gather_bf<<<12500, 256, 0, stream>>>(ax_bf,   norm, off, csr, ax2_bf);

    gemm_bn<<<782, 256, 0, stream>>>(feat_bf, ax_bf, ax2_bf, wcT, bias, snorm,
                                     t_bf, gsums, gsq);
    bn_finalize<<<1, 128, 0, stream>>>(gsums, gsq, gamma, beta, scale, shift);
    epilogue   <<<6250, 256, 0, stream>>>(t_bf, feat, scale, shift, out);
}

// Round 8
// 185.412 us; speedup vs baseline: 15.7985x; 1.0655x over previous
//
#include <hip/hip_runtime.h>
#include <hip/hip_bf16.h>

#define NN 50000
#define NE 800000
#define DD 128
#define BN_EPS 1e-5f
#define SCAN_G 98    // 98*512 = 50176 >= NN

typedef unsigned short ushort_t;
typedef unsigned int uint_t;
typedef __attribute__((ext_vector_type(8))) short short8v;   // 8 x bf16 (4 VGPR)
typedef __attribute__((ext_vector_type(4))) float f32x4;

__device__ __forceinline__ float b2f(ushort_t u) {
    union { uint_t i; float f; } v; v.i = ((uint_t)u) << 16; return v.f;
}
__device__ __forceinline__ ushort_t f2b(float f) {
    uint_t u = __float_as_uint(f);
    u += 0x7FFFu + ((u >> 16) & 1u);   // RNE
    return (ushort_t)(u >> 16);
}
__device__ __forceinline__ void atomAdd(float* p, float v) { unsafeAtomicAdd(p, v); }

// ---------- graph prep ----------
// epos[e] = position of edge e within its dst bucket; cnt ends as deg.
__global__ void epos_kernel(const int* __restrict__ dst, int* __restrict__ cnt,
                            int* __restrict__ epos) {
    int e = blockIdx.x * 256 + threadIdx.x;
    if (e < NE) epos[e] = atomicAdd(&cnt[dst[e]], 1);
}

// pass 1: per-block (512 elems) sums; also emits norm = rsqrt(max(deg,1))
__global__ __launch_bounds__(512) void scan_part(const int* __restrict__ deg,
                                                 int* __restrict__ part,
                                                 float* __restrict__ norm) {
    int i = blockIdx.x * 512 + threadIdx.x;
    int v = (i < NN) ? deg[i] : 0;
    if (i < NN) norm[i] = rsqrtf((float)max(v, 1));
    int s = v;
    #pragma unroll
    for (int k = 1; k < 64; k <<= 1) s += __shfl_xor(s, k);
    __shared__ int wsum[8];
    if ((threadIdx.x & 63) == 0) wsum[threadIdx.x >> 6] = s;
    __syncthreads();
    if (threadIdx.x == 0) {
        int t = 0;
        #pragma unroll
        for (int k = 0; k < 8; ++k) t += wsum[k];
        part[blockIdx.x] = t;
    }
}

// pass 2: exclusive scan of the 98 block sums
__global__ __launch_bounds__(128) void scan_mid(const int* __restrict__ part,
                                                int* __restrict__ base) {
    __shared__ int sh[128];
    int t = threadIdx.x;
    sh[t] = (t < SCAN_G) ? part[t] : 0;
    __syncthreads();
    for (int s = 1; s < 128; s <<= 1) {
        int u = (t >= s) ? sh[t - s] : 0;
        __syncthreads();
        sh[t] += u;
        __syncthreads();
    }
    base[t] = t ? sh[t - 1] : 0;
}

// pass 3: block-local exclusive scan + base -> off
__global__ __launch_bounds__(512) void scan_final(const int* __restrict__ deg,
                                                  const int* __restrict__ base,
                                                  int* __restrict__ off) {
    int i = blockIdx.x * 512 + threadIdx.x;
    int lane = threadIdx.x & 63, wv = threadIdx.x >> 6;
    int v = (i < NN) ? deg[i] : 0;
    int incl = v;
    #pragma unroll
    for (int s = 1; s < 64; s <<= 1) {
        int u = __shfl_up(incl, s);
        if (lane >= s) incl += u;
    }
    __shared__ int wsum[8];
    if (lane == 63) wsum[wv] = incl;
    __syncthreads();
    int woff = 0;
    for (int k = 0; k < wv; ++k) woff += wsum[k];
    int excl = base[blockIdx.x] + woff + incl - v;
    if (i < NN) off[i] = excl;
    if (blockIdx.x == 0 && threadIdx.x == 0) off[NN] = NE;
}

// csr[off[dst]+epos] = (src, bits(norm[src])) — atomic-free scatter
__global__ void fill_kernel(const int* __restrict__ src, const int* __restrict__ dst,
                            const int* __restrict__ epos, const int* __restrict__ off,
                            const float* __restrict__ norm, int2* __restrict__ csr) {
    int e = blockIdx.x * 256 + threadIdx.x;
    if (e >= NE) return;
    int s = src[e];
    int p = off[dst[e]] + epos[e];
    csr[p] = make_int2(s, __float_as_int(norm[s]));
}

// ---------- conversions ----------
__global__ void f2bf_kernel(const float* __restrict__ in, ushort_t* __restrict__ out) {
    int i = blockIdx.x * 256 + threadIdx.x;   // per 4 elems
    if (i >= NN * DD / 4) return;
    float4 v = reinterpret_cast<const float4*>(in)[i];
    ushort4 o = { f2b(v.x), f2b(v.y), f2b(v.z), f2b(v.w) };
    reinterpret_cast<ushort4*>(out)[i] = o;
}

// WcT[d][k] (128 x 384 bf16): k<128: W1-W3; k<256: -W2; else 2*W3
__global__ void wct_kernel(const float* __restrict__ W1, const float* __restrict__ W2,
                           const float* __restrict__ W3, ushort_t* __restrict__ wcT) {
    int i = blockIdx.x * 256 + threadIdx.x;
    if (i >= DD * 384) return;
    int d = i / 384, k = i % 384;
    float v;
    if (k < 128)      v = W1[k * DD + d] - W3[k * DD + d];
    else if (k < 256) v = -W2[(k - 128) * DD + d];
    else              v = 2.0f * W3[(k - 256) * DD + d];
    wcT[i] = f2b(v);
}

// ---------- message passing (bf16 in, bf16 out) ----------
// wave per node; HALF-WAVE per edge (lane loads uint2 = 4 bf16 cols).
// 4-deep unroll per half => 8 independent row loads in flight per wave.
__global__ __launch_bounds__(256) void gather_bf(const ushort_t* __restrict__ x,
                                                 const float* __restrict__ norm,
                                                 const int* __restrict__ off,
                                                 const int2* __restrict__ csr,
                                                 ushort_t* __restrict__ out) {
    int wid = (blockIdx.x << 2) + (threadIdx.x >> 6);
    int lane = threadIdx.x & 63;
    int h = lane >> 5, l5 = lane & 31;
    int jb = off[wid], je = off[wid + 1];
    const uint2* xp = reinterpret_cast<const uint2*>(x);   // row = 32 x uint2
    float a0 = 0.f, a1 = 0.f, a2 = 0.f, a3 = 0.f;
    int j = jb;
    for (; j + 8 <= je; j += 8) {
        int e = j + (h << 2);
        int2 c0 = csr[e + 0];
        int2 c1 = csr[e + 1];
        int2 c2 = csr[e + 2];
        int2 c3 = csr[e + 3];
        uint2 v0 = xp[c0.x * 32 + l5];
        uint2 v1 = xp[c1.x * 32 + l5];
        uint2 v2 = xp[c2.x * 32 + l5];
        uint2 v3 = xp[c3.x * 32 + l5];
        float n0 = __int_as_float(c0.y), n1 = __int_as_float(c1.y);
        float n2 = __int_as_float(c2.y), n3 = __int_as_float(c3.y);
        a0 = fmaf(n0, b2f((ushort_t)v0.x), a0);
        a1 = fmaf(n0, b2f((ushort_t)(v0.x >> 16)), a1);
        a2 = fmaf(n0, b2f((ushort_t)v0.y), a2);
        a3 = fmaf(n0, b2f((ushort_t)(v0.y >> 16)), a3);
        a0 = fmaf(n1, b2f((ushort_t)v1.x), a0);
        a1 = fmaf(n1, b2f((ushort_t)(v1.x >> 16)), a1);
        a2 = fmaf(n1, b2f((ushort_t)v1.y), a2);
        a3 = fmaf(n1, b2f((ushort_t)(v1.y >> 16)), a3);
        a0 = fmaf(n2, b2f((ushort_t)v2.x), a0);
        a1 = fmaf(n2, b2f((ushort_t)(v2.x >> 16)), a1);
        a2 = fmaf(n2, b2f((ushort_t)v2.y), a2);
        a3 = fmaf(n2, b2f((ushort_t)(v2.y >> 16)), a3);
        a0 = fmaf(n3, b2f((ushort_t)v3.x), a0);
        a1 = fmaf(n3, b2f((ushort_t)(v3.x >> 16)), a1);
        a2 = fmaf(n3, b2f((ushort_t)v3.y), a2);
        a3 = fmaf(n3, b2f((ushort_t)(v3.y >> 16)), a3);
    }
    for (; j + 2 <= je; j += 2) {
        int2 c = csr[j + h];
        uint2 v = xp[c.x * 32 + l5];
        float n = __int_as_float(c.y);
        a0 = fmaf(n, b2f((ushort_t)v.x), a0);
        a1 = fmaf(n, b2f((ushort_t)(v.x >> 16)), a1);
        a2 = fmaf(n, b2f((ushort_t)v.y), a2);
        a3 = fmaf(n, b2f((ushort_t)(v.y >> 16)), a3);
    }
    if (j < je && h == 0) {
        int2 c = csr[j];
        uint2 v = xp[c.x * 32 + l5];
        float n = __int_as_float(c.y);
        a0 = fmaf(n, b2f((ushort_t)v.x), a0);
        a1 = fmaf(n, b2f((ushort_t)(v.x >> 16)), a1);
        a2 = fmaf(n, b2f((ushort_t)v.y), a2);
        a3 = fmaf(n, b2f((ushort_t)(v.y >> 16)), a3);
    }
    a0 += __shfl_xor(a0, 32);
    a1 += __shfl_xor(a1, 32);
    a2 += __shfl_xor(a2, 32);
    a3 += __shfl_xor(a3, 32);
    if (h == 0) {
        float nd = norm[wid];
        uint2 o;
        o.x = (uint_t)f2b(nd * a0) | ((uint_t)f2b(nd * a1) << 16);
        o.y = (uint_t)f2b(nd * a2) | ((uint_t)f2b(nd * a3) << 16);
        reinterpret_cast<uint2*>(out)[wid * 32 + l5] = o;
    }
}

// ---------- MFMA GEMM + BN partials ----------
__global__ __launch_bounds__(256) void gemm_bn(
    const ushort_t* __restrict__ feat_bf, const ushort_t* __restrict__ ax_bf,
    const ushort_t* __restrict__ ax2_bf, const ushort_t* __restrict__ wcT,
    const float* __restrict__ bias, const float* __restrict__ snorm,
    ushort_t* __restrict__ t_out, float* __restrict__ gsums, float* __restrict__ gsq)
{
    __shared__ ushort_t As[64 * 128];    // 16 KB, XOR-swizzled
    __shared__ ushort_t Bs[128 * 128];   // 32 KB, XOR-swizzled
    int tid = threadIdx.x;
    int w = tid >> 6, lane = tid & 63;
    int row0 = blockIdx.x * 64;

    f32x4 acc[8] = {};

    #pragma unroll
    for (int kt = 0; kt < 3; ++kt) {
        const ushort_t* S = (kt == 0) ? feat_bf : (kt == 1) ? ax_bf : ax2_bf;
        __syncthreads();
        {
            int r = tid >> 2, q = tid & 3;
            int grow = min(row0 + r, NN - 1);
            const char* gsrc = (const char*)(S + grow * DD);
            char* dbase = (char*)As + r * 256;
            int sw = (r & 7) << 4;
            #pragma unroll
            for (int c = 0; c < 4; ++c) {
                int cb = (q * 4 + c) * 16;
                *(short8v*)(dbase + (cb ^ sw)) = *(const short8v*)(gsrc + cb);
            }
        }
        {
            int cidx = tid >> 1, hh = tid & 1;
            const char* gsrc = (const char*)(wcT + cidx * 384 + kt * 128);
            char* dbase = (char*)Bs + cidx * 256;
            int sw = (cidx & 7) << 4;
            #pragma unroll
            for (int c = 0; c < 8; ++c) {
                int cb = (hh * 8 + c) * 16;
                *(short8v*)(dbase + (cb ^ sw)) = *(const short8v*)(gsrc + cb);
            }
        }
        __syncthreads();
        int arow = w * 16 + (lane & 15);
        int asw = (arow & 7) << 4;
        #pragma unroll
        for (int ks = 0; ks < 4; ++ks) {
            int kb = ks * 64 + ((lane >> 4) << 4);
            short8v a = *(const short8v*)((const char*)As + arow * 256 + (kb ^ asw));
            #pragma unroll
            for (int cf = 0; cf < 8; ++cf) {
                int col = cf * 16 + (lane & 15);
                short8v b = *(const short8v*)((const char*)Bs + col * 256 + (kb ^ ((col & 7) << 4)));
                acc[cf] = __builtin_amdgcn_mfma_f32_16x16x32_bf16(a, b, acc[cf], 0, 0, 0);
            }
        }
    }

    int q = lane >> 4, c0 = lane & 15;
    int rbase = row0 + w * 16 + q * 4;
    float sn[4];
    #pragma unroll
    for (int i = 0; i < 4; ++i) sn[i] = (rbase + i < NN) ? snorm[rbase + i] : 0.f;

    float s1[8], s2[8];
    #pragma unroll
    for (int cf = 0; cf < 8; ++cf) {
        s1[cf] = 0.f; s2[cf] = 0.f;
        int col = cf * 16 + c0;
        float bc = bias[col];
        #pragma unroll
        for (int i = 0; i < 4; ++i) {
            int row = rbase + i;
            if (row < NN) {
                float t = (acc[cf][i] + bc) * sn[i];
                t_out[row * DD + col] = f2b(t);
                s1[cf] += t; s2[cf] += t * t;
            }
        }
    }
    #pragma unroll
    for (int cf = 0; cf < 8; ++cf) {
        s1[cf] += __shfl_xor(s1[cf], 16); s1[cf] += __shfl_xor(s1[cf], 32);
        s2[cf] += __shfl_xor(s2[cf], 16); s2[cf] += __shfl_xor(s2[cf], 32);
    }
    if (q == 0) {
        int slot = (blockIdx.x & 31) * DD;
        #pragma unroll
        for (int cf = 0; cf < 8; ++cf) {
            atomAdd(&gsums[slot + cf * 16 + c0], s1[cf]);
            atomAdd(&gsq[slot + cf * 16 + c0], s2[cf]);
        }
    }
}

__global__ void bn_finalize(const float* __restrict__ gsums, const float* __restrict__ gsq,
                            const float* __restrict__ gamma,
                            const float* __restrict__ beta,
                            float* __restrict__ scale, float* __restrict__ shift) {
    int d = threadIdx.x;  // 128
    float s1 = 0.f, s2 = 0.f;
    for (int c = 0; c < 32; ++c) { s1 += gsums[c * DD + d]; s2 += gsq[c * DD + d]; }
    float mean = s1 / (float)NN;
    float var  = s2 / (float)NN - mean * mean;
    float sc = gamma[d] * rsqrtf(var + BN_EPS);
    scale[d] = sc;
    shift[d] = beta[d] - mean * sc;
}

// out = feat_bf + relu(t*scale + shift)   (both bf16 inputs, f32 out)
__global__ void epilogue(const ushort_t* __restrict__ t, const ushort_t* __restrict__ featb,
                         const float* __restrict__ scale, const float* __restrict__ shift,
                         float* __restrict__ out) {
    int i = blockIdx.x * 256 + threadIdx.x;
    if (i >= NN * DD / 4) return;
    int d0 = (i << 2) & 127;
    ushort4 tv = reinterpret_cast<const ushort4*>(t)[i];
    ushort4 fv = reinterpret_cast<const ushort4*>(featb)[i];
    float4 o;
    o.x = b2f(fv.x) + fmaxf(b2f(tv.x) * scale[d0 + 0] + shift[d0 + 0], 0.f);
    o.y = b2f(fv.y) + fmaxf(b2f(tv.y) * scale[d0 + 1] + shift[d0 + 1], 0.f);
    o.z = b2f(fv.z) + fmaxf(b2f(tv.z) * scale[d0 + 2] + shift[d0 + 2], 0.f);
    o.w = b2f(fv.w) + fmaxf(b2f(tv.w) * scale[d0 + 3] + shift[d0 + 3], 0.f);
    reinterpret_cast<float4*>(out)[i] = o;
}

extern "C" void kernel_launch(void* const* d_in, const int* in_sizes, int n_in,
                              void* d_out, int out_size, void* d_ws, size_t ws_size,
                              hipStream_t stream) {
    const float* feat  = (const float*)d_in[0];
    const float* snorm = (const float*)d_in[1];
    const float* W1    = (const float*)d_in[2];
    const float* W2    = (const float*)d_in[3];
    const float* W3    = (const float*)d_in[4];
    const float* bias  = (const float*)d_in[5];
    const float* gamma = (const float*)d_in[6];
    const float* beta  = (const float*)d_in[7];
    const int* esrc = (const int*)d_in[8];
    const int* edst = (const int*)d_in[9];
    float* out = (float*)d_out;

    char* ws = (char*)d_ws;
    ushort_t* t_bf    = (ushort_t*)(ws);                 // 12,800,000 (gemm output)
    int*      epos    = (int*)     (ws);                 //  3,200,000 ALIAS of t_bf
                                                         //  (epos dead before gemm_bn runs)
    ushort_t* feat_bf = (ushort_t*)(ws + 12800000);      // 12,800,000
    ushort_t* ax_bf   = (ushort_t*)(ws + 25600000);      // 12,800,000
    ushort_t* ax2_bf  = (ushort_t*)(ws + 38400000);      // 12,800,000
    int2*     csr     = (int2*)    (ws + 51200000);      //  6,400,000 (src, norm bits)
    float*    norm    = (float*)   (ws + 57600000);      //    200,000
    int*      cnt     = (int*)     (ws + 57800000);      //    200,000 (-> deg)
    float*    gsums   = (float*)   (ws + 58000000);      //     16,384
    float*    gsq     = (float*)   (ws + 58016384);      //     16,384
    int*      off     = (int*)     (ws + 58032768);      //    200,064
    int*      part    = (int*)     (ws + 58232832);      //        512
    int*      base    = (int*)     (ws + 58233344);      //        512
    float*    scale   = (float*)   (ws + 58233856);      //        512
    float*    shift   = (float*)   (ws + 58234368);      //        512
    ushort_t* wcT     = (ushort_t*)(ws + 58234880);      //     98,304 (end 58,333,184)

    hipMemsetAsync(ws + 57800000, 0, 232768, stream);    // cnt, gsums, gsq

    epos_kernel<<<3125, 256, 0, stream>>>(edst, cnt, epos);
    scan_part  <<<SCAN_G, 512, 0, stream>>>(cnt, part, norm);
    scan_mid   <<<1, 128, 0, stream>>>(part, base);
    scan_final <<<SCAN_G, 512, 0, stream>>>(cnt, base, off);
    fill_kernel<<<3125, 256, 0, stream>>>(esrc, edst, epos, off, norm, csr);

    f2bf_kernel<<<6250, 256, 0, stream>>>(feat, feat_bf);
    wct_kernel <<<192,  256, 0, stream>>>(W1, W2, W3, wcT);

    gather_bf<<<12500, 256, 0, stream>>>(feat_bf, norm, off, csr, ax_bf);
    gather_bf<<<12500, 256, 0, stream>>>(ax_bf,   norm, off, csr, ax2_bf);

    gemm_bn<<<782, 256, 0, stream>>>(feat_bf, ax_bf, ax2_bf, wcT, bias, snorm,
                                     t_bf, gsums, gsq);
    bn_finalize<<<1, 128, 0, stream>>>(gsums, gsq, gamma, beta, scale, shift);
    epilogue   <<<6250, 256, 0, stream>>>(t_bf, feat_bf, scale, shift, out);
}